// Round 15
// baseline (651.722 us; speedup 1.0000x reference)
//
#include <hip/hip_runtime.h>
#include <hip/hip_bf16.h>

// Problem constants (fixed by reference setup_inputs)
#define S_ROWS 4096
#define Q_ROWS 8192
#define DIM 256
#define N_SEL 19       // selection events (20 scan steps)
#define COLSPLIT 32    // phase-B column splits (128 cols per block)
#define BM 128         // phase-B rows per block
#define LDST 36        // phase-B LDS row stride (floats)
#define CB 32          // phase-C blocks
#define CT 1024        // phase-C threads per block
#define CR 256         // phase-C rows per block (4 threads per row)
#define SLOTS 4        // candidate slots per block per iteration

// Workspace layout (floats)
#define WS_INV_Q 0
#define WS_QQ    (WS_INV_Q + Q_ROWS)
#define WS_INV_S (WS_QQ + Q_ROWS)
#define WS_PP    (WS_INV_S + S_ROWS)
#define WS_TOP3P (WS_PP + S_ROWS)                    // [COLSPLIT][Q_ROWS][4]
#define WS_BMIN  (WS_TOP3P + COLSPLIT * Q_ROWS * 4)  // [32][CB]
#define WS_CANDU (WS_BMIN + 32 * CB)                 // [32][CB*SLOTS]
#define WS_CANDI (WS_CANDU + 32 * CB * SLOTS)        // [32][CB*SLOTS] (int)
#define WS_FLAGS (WS_CANDI + 32 * CB * SLOTS)        // unsigned [32*CB] barrier flags

// ---------------------------------------------------------------------------
__global__ void norm_rows(const float* __restrict__ x, float* __restrict__ inv,
                          float* __restrict__ ssq, int nrows) {
    int w = (blockIdx.x * blockDim.x + threadIdx.x) >> 6;
    int lane = threadIdx.x & 63;
    if (w >= nrows) return;
    float4 v = reinterpret_cast<const float4*>(x + (size_t)w * DIM)[lane];
    float s = v.x * v.x + v.y * v.y + v.z * v.z + v.w * v.w;
#pragma unroll
    for (int o = 1; o < 64; o <<= 1) s += __shfl_xor(s, o, 64);
    float invn = 1.0f / sqrtf(s);
    float t = v.x * invn; float u = t * t;
    t = v.y * invn; u += t * t;
    t = v.z * invn; u += t * t;
    t = v.w * invn; u += t * t;
#pragma unroll
    for (int o = 1; o < 64; o <<= 1) u += __shfl_xor(u, o, 64);
    if (lane == 0) { inv[w] = invn; ssq[w] = u; }
}

// ---------------------------------------------------------------------------
// MUST be launched with >= max(32*CB, n_extra) threads (R12 bug: under-sized
// grid left "ones" outputs unwritten).
__global__ void init_ws(unsigned* __restrict__ flags, float* __restrict__ out, int n_extra) {
    int t = blockIdx.x * blockDim.x + threadIdx.x;
    if (t < 32 * CB) flags[t] = 0u;
    if (t < n_extra) out[Q_ROWS + t] = 1.0f;
}

// ---------------------------------------------------------------------------
__device__ __forceinline__ void t3ins(float (&t3)[3], float d) {
    float mx = fmaxf(fmaxf(t3[0], t3[1]), t3[2]);
    if (d < mx) {
        if (t3[0] == mx) t3[0] = d;
        else if (t3[1] == mx) t3[1] = d;
        else t3[2] = d;
    }
}

__device__ __forceinline__ float smean3(float a, float b, float c) {
    float lo = fminf(fminf(a, b), c);
    float hi = fmaxf(fmaxf(a, b), c);
    float md = fminf(fmaxf(a, b), fminf(fmaxf(b, c), fmaxf(a, c)));
    return ((lo + md) + hi) * (1.0f / 3.0f);
}

// ---------------------------------------------------------------------------
// Phase B: fp32 GEMM + per-row top-3. R11's proven quadrant body VERBATIM
// (A+B LDS-staged, full-line loads, XOR swizzle write+read).
// VGPR discipline (R3..R14 data): backend targets 2x launch_bounds min-waves:
//   min4->VGPR64 (R6, spill 3.7GB) | min3->84 (R7..R14, chronic 65-440MB
//   spill) | min2->128 (R3, clean). LDS 36KB caps occupancy at 4 blocks/CU
//   regardless, and 128 VGPR = 4 waves/SIMD matches that cap exactly ->
//   (256,2) removes the spill without losing occupancy.
__launch_bounds__(256, 2)
__global__ void knn_support_kernel(const float* __restrict__ qf, const float* __restrict__ sf,
                                   const float* __restrict__ inv_q, const float* __restrict__ inv_s,
                                   const float* __restrict__ qq, const float* __restrict__ pp,
                                   float* __restrict__ top3part) {
    __shared__ __align__(16) float As[BM * LDST];
    __shared__ __align__(16) float Bs[BM * LDST];

    int b0 = blockIdx.x;
    int rb = (b0 & 63) * BM;
    int cs = b0 >> 6;            // 0..31
    int cb = cs * 128;
    int tid = threadIdx.x;
    int tx = tid & 15, ty = tid >> 4;

    float t3[8][3];
#pragma unroll
    for (int i = 0; i < 8; ++i) t3[i][0] = t3[i][1] = t3[i][2] = INFINITY;

    float acc[8][8];
#pragma unroll
    for (int i = 0; i < 8; ++i)
#pragma unroll
        for (int j = 0; j < 8; ++j) acc[i][j] = 0.0f;

    for (int kt = 0; kt < 8; ++kt) {
        int ko = kt * 32;
        __syncthreads();   // previous tile's readers done before overwrite
#pragma unroll
        for (int q = 0; q < 4; ++q) {
            int idx = q * 256 + tid;
            int row = idx >> 3, f4 = idx & 7;
            int slot = f4 ^ ((row >> 1) & 7);
            float4 a = *reinterpret_cast<const float4*>(qf + (size_t)(rb + row) * DIM + ko + f4 * 4);
            *reinterpret_cast<float4*>(As + row * LDST + (slot << 2)) = a;
            float4 b = *reinterpret_cast<const float4*>(sf + (size_t)(cb + row) * DIM + ko + f4 * 4);
            *reinterpret_cast<float4*>(Bs + row * LDST + (slot << 2)) = b;
        }
        __syncthreads();
#pragma unroll
        for (int K = 0; K < 8; ++K) {
            int sA = ((K ^ (ty >> 1)) & 7) << 2;
            int sB = ((K ^ (tx >> 1)) & 7) << 2;
            float4 av[4], bva[4], bvb[4];
            // segment 1: i0-3 x j0-3
#pragma unroll
            for (int i = 0; i < 4; ++i)
                av[i] = *reinterpret_cast<const float4*>(As + (ty + 16 * i) * LDST + sA);
#pragma unroll
            for (int j = 0; j < 4; ++j)
                bva[j] = *reinterpret_cast<const float4*>(Bs + (tx + 16 * j) * LDST + sB);
#pragma unroll
            for (int i = 0; i < 4; ++i)
#pragma unroll
                for (int j = 0; j < 4; ++j) {
                    acc[i][j] += av[i].x * bva[j].x;
                    acc[i][j] += av[i].y * bva[j].y;
                    acc[i][j] += av[i].z * bva[j].z;
                    acc[i][j] += av[i].w * bva[j].w;
                }
            // segment 2: i0-3 x j4-7
#pragma unroll
            for (int j = 0; j < 4; ++j)
                bvb[j] = *reinterpret_cast<const float4*>(Bs + (tx + 16 * (4 + j)) * LDST + sB);
#pragma unroll
            for (int i = 0; i < 4; ++i)
#pragma unroll
                for (int j = 0; j < 4; ++j) {
                    acc[i][4 + j] += av[i].x * bvb[j].x;
                    acc[i][4 + j] += av[i].y * bvb[j].y;
                    acc[i][4 + j] += av[i].z * bvb[j].z;
                    acc[i][4 + j] += av[i].w * bvb[j].w;
                }
            // segment 3: i4-7 x j4-7 (av overwritten)
#pragma unroll
            for (int i = 0; i < 4; ++i)
                av[i] = *reinterpret_cast<const float4*>(As + (ty + 16 * (4 + i)) * LDST + sA);
#pragma unroll
            for (int i = 0; i < 4; ++i)
#pragma unroll
                for (int j = 0; j < 4; ++j) {
                    acc[4 + i][4 + j] += av[i].x * bvb[j].x;
                    acc[4 + i][4 + j] += av[i].y * bvb[j].y;
                    acc[4 + i][4 + j] += av[i].z * bvb[j].z;
                    acc[4 + i][4 + j] += av[i].w * bvb[j].w;
                }
            // segment 4: i4-7 x j0-3 (bva reloaded)
#pragma unroll
            for (int j = 0; j < 4; ++j)
                bva[j] = *reinterpret_cast<const float4*>(Bs + (tx + 16 * j) * LDST + sB);
#pragma unroll
            for (int i = 0; i < 4; ++i)
#pragma unroll
                for (int j = 0; j < 4; ++j) {
                    acc[4 + i][j] += av[i].x * bva[j].x;
                    acc[4 + i][j] += av[i].y * bva[j].y;
                    acc[4 + i][j] += av[i].z * bva[j].z;
                    acc[4 + i][j] += av[i].w * bva[j].w;
                }
        }
    }
    // epilogue: scale, distance, top-3
    {
        float ivb[8], ppc[8];
#pragma unroll
        for (int j = 0; j < 8; ++j) {
            ivb[j] = inv_s[cb + tx + 16 * j];
            ppc[j] = pp[cb + tx + 16 * j];
        }
#pragma unroll
        for (int i = 0; i < 8; ++i) {
            int r = rb + ty + 16 * i;
            float iva = inv_q[r];
            float qqr = qq[r];
#pragma unroll
            for (int j = 0; j < 8; ++j) {
                float dot = acc[i][j] * iva * ivb[j];
                float d2 = qqr + ppc[j] - 2.0f * dot;
                float d = sqrtf(fmaxf(d2, 1e-12f));
                t3ins(t3[i], d);
            }
        }
    }

    // merge per-row top3 across the 16 tx lanes (in-wave butterfly)
#pragma unroll
    for (int off = 1; off < 16; off <<= 1) {
#pragma unroll
        for (int i = 0; i < 8; ++i) {
            float o0 = __shfl_xor(t3[i][0], off, 64);
            float o1 = __shfl_xor(t3[i][1], off, 64);
            float o2 = __shfl_xor(t3[i][2], off, 64);
            t3ins(t3[i], o0);
            t3ins(t3[i], o1);
            t3ins(t3[i], o2);
        }
    }
    if (tx == 0) {
#pragma unroll
        for (int i = 0; i < 8; ++i) {
            float* dst = top3part + ((size_t)cs * Q_ROWS + rb + ty + 16 * i) * 4;
            dst[0] = t3[i][0]; dst[1] = t3[i][1]; dst[2] = t3[i][2]; dst[3] = 0.0f;
        }
    }
}

// ---------------------------------------------------------------------------
// Phase C (R13/R14 proven, ~95us): 20 scan steps, one cooperative kernel.
// No serialized RMW chains: per-block slots + per-block release flags,
// wave-parallel poll.
__global__ void iterate_select(const float* __restrict__ qf, const float* __restrict__ inv_q,
                               const float* __restrict__ qq, const float* __restrict__ top3part,
                               float* __restrict__ out, float* __restrict__ bmins,
                               float* __restrict__ candU, int* __restrict__ candI,
                               unsigned* __restrict__ flags) {
    __shared__ float t3s[CR][3];
    __shared__ float invs[CR], qqs[CR], scs[CR];
    __shared__ int kn[CR];
    __shared__ __align__(16) float qfc[DIM];
    __shared__ float red[CT / 64];
    __shared__ float bmin_sh, kth_sh;
    __shared__ int lidx[16];
    __shared__ int lcnt, ccnt;

    int tid = threadIdx.x;
    int bid = blockIdx.x;
    int rbase = bid * CR;
    int lane = tid & 63, wv = tid >> 6;

    if (tid < CR) {
        int r = rbase + tid;
        float b3[3] = {INFINITY, INFINITY, INFINITY};
        for (int csq = 0; csq < COLSPLIT; ++csq) {
            const float* p = top3part + ((size_t)csq * Q_ROWS + r) * 4;
            t3ins(b3, p[0]); t3ins(b3, p[1]); t3ins(b3, p[2]);
        }
        t3s[tid][0] = b3[0]; t3s[tid][1] = b3[1]; t3s[tid][2] = b3[2];
        invs[tid] = inv_q[r];
        qqs[tid] = qq[r];
        kn[tid] = 0;
    }
    __syncthreads();

    for (int t = 0; t <= N_SEL; ++t) {
        if (t > 0) {
            if (tid == 0) lcnt = 0;
            if (wv == 0 && lane < CB) {
                float v = bmins[(t - 1) * CB + lane];
#pragma unroll
                for (int o = 1; o < CB; o <<= 1) v = fminf(v, __shfl_xor(v, o, 64));
                if (lane == 0) kth_sh = v;
            }
            __syncthreads();
            float kth = kth_sh;
            if (tid < CB * SLOTS) {
                float u = candU[(t - 1) * CB * SLOTS + tid];
                if (u <= kth) {
                    int p = atomicAdd(&lcnt, 1);
                    if (p < 16) lidx[p] = candI[(t - 1) * CB * SLOTS + tid];
                }
            }
            __syncthreads();
            int m = lcnt < 16 ? lcnt : 16;
            for (int j = 0; j < m; ++j) {
                int c = lidx[j];
                if (tid == 0 && c >= rbase && c < rbase + CR) kn[c - rbase] = 1;
                if (tid < DIM) qfc[tid] = qf[(size_t)c * DIM + tid] * inv_q[c];
                __syncthreads();
                float qqc = qq[c];
                int row = tid >> 2, sub = tid & 3;
                const float4* rp = reinterpret_cast<const float4*>(qf + (size_t)(rbase + row) * DIM);
                const float4* cp = reinterpret_cast<const float4*>(qfc);
                float si = invs[row];
                float d = 0.0f;
#pragma unroll
                for (int i2 = 0; i2 < 16; ++i2) {
                    float4 v = rp[sub + 4 * i2];
                    float4 w = cp[sub + 4 * i2];
                    d += (v.x * si) * w.x;
                    d += (v.y * si) * w.y;
                    d += (v.z * si) * w.z;
                    d += (v.w * si) * w.w;
                }
                d += __shfl_xor(d, 1, 64);
                d += __shfl_xor(d, 2, 64);
                if (sub == 0) {
                    float d2 = qqs[row] + qqc - 2.0f * d;
                    float dist = sqrtf(fmaxf(d2, 1e-12f));
                    float b3[3] = {t3s[row][0], t3s[row][1], t3s[row][2]};
                    t3ins(b3, dist);
                    t3s[row][0] = b3[0]; t3s[row][1] = b3[1]; t3s[row][2] = b3[2];
                }
                __syncthreads();
            }
            __syncthreads();
        }

        if (t == N_SEL) {
            if (tid < CR)
                out[rbase + tid] = 1.0f - smean3(t3s[tid][0], t3s[tid][1], t3s[tid][2]);
            return;
        }

        if (tid == 0) ccnt = 0;
        if (tid < CR)
            scs[tid] = kn[tid] ? INFINITY : smean3(t3s[tid][0], t3s[tid][1], t3s[tid][2]);
        __syncthreads();

        float mn = (tid < CR) ? scs[tid] : INFINITY;
#pragma unroll
        for (int o = 1; o < 64; o <<= 1) mn = fminf(mn, __shfl_xor(mn, o, 64));
        if (lane == 0) red[wv] = mn;
        __syncthreads();
        if (tid == 0) {
            float v = red[0];
#pragma unroll
            for (int i = 1; i < CT / 64; ++i) v = fminf(v, red[i]);
            bmin_sh = v;
            bmins[t * CB + bid] = v;
        }
        __syncthreads();
        float bmin = bmin_sh;
        if (tid < CR && scs[tid] == bmin) {
            int p = atomicAdd(&ccnt, 1);
            if (p < SLOTS) {
                candU[t * CB * SLOTS + bid * SLOTS + p] = scs[tid];
                candI[t * CB * SLOTS + bid * SLOTS + p] = rbase + tid;
            }
        }
        __syncthreads();
        if (tid == 0) {
            for (int p = ccnt; p < SLOTS; ++p) {
                candU[t * CB * SLOTS + bid * SLOTS + p] = INFINITY;
                candI[t * CB * SLOTS + bid * SLOTS + p] = 0;
            }
            __hip_atomic_store(&flags[t * CB + bid], 1u,
                               __ATOMIC_RELEASE, __HIP_MEMORY_SCOPE_AGENT);
        }
        if (wv == 0) {
            for (;;) {
                bool ok = (lane >= CB) ||
                          (__hip_atomic_load(&flags[t * CB + lane],
                                             __ATOMIC_RELAXED, __HIP_MEMORY_SCOPE_AGENT) != 0u);
                if (__all(ok)) break;
                __builtin_amdgcn_s_sleep(1);
            }
            __threadfence();
        }
        __syncthreads();
    }
}

// ---------------------------------------------------------------------------
extern "C" void kernel_launch(void* const* d_in, const int* in_sizes, int n_in,
                              void* d_out, int out_size, void* d_ws, size_t ws_size,
                              hipStream_t stream) {
    const float* sfeat = (const float*)d_in[0];
    const float* qfeat = (const float*)d_in[2];
    float* out = (float*)d_out;

    float* ws = (float*)d_ws;
    float* inv_q = ws + WS_INV_Q;
    float* qq    = ws + WS_QQ;
    float* inv_s = ws + WS_INV_S;
    float* pp    = ws + WS_PP;
    float* top3p = ws + WS_TOP3P;
    float* bmins = ws + WS_BMIN;
    float* candU = ws + WS_CANDU;
    int* candI   = (int*)(ws + WS_CANDI);
    unsigned* flags = (unsigned*)(ws + WS_FLAGS);

    int n_extra = out_size - Q_ROWS;
    if (n_extra < 0) n_extra = 0;

    norm_rows<<<Q_ROWS * 64 / 256, 256, 0, stream>>>(qfeat, inv_q, qq, Q_ROWS);
    norm_rows<<<S_ROWS * 64 / 256, 256, 0, stream>>>(sfeat, inv_s, pp, S_ROWS);
    init_ws<<<32, 256, 0, stream>>>(flags, out, n_extra);   // 8192 threads >= max(32*CB, n_extra)
    knn_support_kernel<<<64 * COLSPLIT, 256, 0, stream>>>(qfeat, sfeat, inv_q, inv_s, qq, pp, top3p);

    const float* a0 = qfeat; const float* a1 = inv_q; const float* a2 = qq;
    const float* a3 = top3p; float* a4 = out;
    float* a5 = bmins; float* a6 = candU; int* a7 = candI; unsigned* a8 = flags;
    void* cargs[] = {&a0, &a1, &a2, &a3, &a4, &a5, &a6, &a7, &a8};
    hipLaunchCooperativeKernel(iterate_select, dim3(CB), dim3(CT), cargs, 0, stream);
}

// Round 16
// 470.825 us; speedup vs baseline: 1.3842x; 1.3842x over previous
//
#include <hip/hip_runtime.h>
#include <hip/hip_bf16.h>

// Problem constants (fixed by reference setup_inputs)
#define S_ROWS 4096
#define Q_ROWS 8192
#define DIM 256
#define N_SEL 19       // selection events (20 scan steps)
#define COLSPLIT 32    // phase-B column splits (128 cols per block)
#define BM 128         // phase-B rows per block
#define LDST 36        // phase-B LDS row stride (floats)
#define CB 32          // phase-C blocks
#define CT 1024        // phase-C threads per block
#define CR 256         // phase-C rows per block (4 threads per row)
#define SLOTS 4        // candidate slots per block per iteration

// Workspace layout (floats)
#define WS_INV_Q 0
#define WS_QQ    (WS_INV_Q + Q_ROWS)
#define WS_INV_S (WS_QQ + Q_ROWS)
#define WS_PP    (WS_INV_S + S_ROWS)
#define WS_TOP3P (WS_PP + S_ROWS)                    // [COLSPLIT][Q_ROWS][4]
#define WS_BMIN  (WS_TOP3P + COLSPLIT * Q_ROWS * 4)  // [32][CB]
#define WS_CANDU (WS_BMIN + 32 * CB)                 // [32][CB*SLOTS]
#define WS_CANDI (WS_CANDU + 32 * CB * SLOTS)        // [32][CB*SLOTS] (int)
#define WS_FLAGS (WS_CANDI + 32 * CB * SLOTS)        // unsigned [32*CB] barrier flags

// ---------------------------------------------------------------------------
__global__ void norm_rows(const float* __restrict__ x, float* __restrict__ inv,
                          float* __restrict__ ssq, int nrows) {
    int w = (blockIdx.x * blockDim.x + threadIdx.x) >> 6;
    int lane = threadIdx.x & 63;
    if (w >= nrows) return;
    float4 v = reinterpret_cast<const float4*>(x + (size_t)w * DIM)[lane];
    float s = v.x * v.x + v.y * v.y + v.z * v.z + v.w * v.w;
#pragma unroll
    for (int o = 1; o < 64; o <<= 1) s += __shfl_xor(s, o, 64);
    float invn = 1.0f / sqrtf(s);
    float t = v.x * invn; float u = t * t;
    t = v.y * invn; u += t * t;
    t = v.z * invn; u += t * t;
    t = v.w * invn; u += t * t;
#pragma unroll
    for (int o = 1; o < 64; o <<= 1) u += __shfl_xor(u, o, 64);
    if (lane == 0) { inv[w] = invn; ssq[w] = u; }
}

// ---------------------------------------------------------------------------
// MUST be launched with >= max(32*CB, n_extra) threads (R12 bug: under-sized
// grid left "ones" outputs unwritten).
__global__ void init_ws(unsigned* __restrict__ flags, float* __restrict__ out, int n_extra) {
    int t = blockIdx.x * blockDim.x + threadIdx.x;
    if (t < 32 * CB) flags[t] = 0u;
    if (t < n_extra) out[Q_ROWS + t] = 1.0f;
}

// ---------------------------------------------------------------------------
__device__ __forceinline__ void t3ins(float (&t3)[3], float d) {
    float mx = fmaxf(fmaxf(t3[0], t3[1]), t3[2]);
    if (d < mx) {
        if (t3[0] == mx) t3[0] = d;
        else if (t3[1] == mx) t3[1] = d;
        else t3[2] = d;
    }
}

__device__ __forceinline__ float smean3(float a, float b, float c) {
    float lo = fminf(fminf(a, b), c);
    float hi = fmaxf(fmaxf(a, b), c);
    float md = fminf(fmaxf(a, b), fminf(fmaxf(b, c), fmaxf(a, c)));
    return ((lo + md) + hi) * (1.0f / 3.0f);
}

// ---------------------------------------------------------------------------
// Phase B: fp32 GEMM + per-row top-3. R11 EXACT (measured 306-316us x5):
// quadrant inner loop, A+B LDS-staged full-line, XOR swizzle write+read.
// launch_bounds landscape fully mapped across rounds:
//   (256,4) -> VGPR 64, catastrophic spill (R6: WRITE 3.7GB)
//   (256,3) -> VGPR 84, tiny spill (65MB ~ 0.2TB/s, noise) = 306us OPTIMUM
//   (256,2) -> VGPR 128, no spill but bloated stream, occ 21% = 533us (R15)
//   none    -> VGPR 64 compiler-chosen, L2 thrash = 465us (R8)
__launch_bounds__(256, 3)
__global__ void knn_support_kernel(const float* __restrict__ qf, const float* __restrict__ sf,
                                   const float* __restrict__ inv_q, const float* __restrict__ inv_s,
                                   const float* __restrict__ qq, const float* __restrict__ pp,
                                   float* __restrict__ top3part) {
    __shared__ __align__(16) float As[BM * LDST];
    __shared__ __align__(16) float Bs[BM * LDST];

    int b0 = blockIdx.x;
    int rb = (b0 & 63) * BM;
    int cs = b0 >> 6;            // 0..31
    int cb = cs * 128;
    int tid = threadIdx.x;
    int tx = tid & 15, ty = tid >> 4;

    float t3[8][3];
#pragma unroll
    for (int i = 0; i < 8; ++i) t3[i][0] = t3[i][1] = t3[i][2] = INFINITY;

    float acc[8][8];
#pragma unroll
    for (int i = 0; i < 8; ++i)
#pragma unroll
        for (int j = 0; j < 8; ++j) acc[i][j] = 0.0f;

    for (int kt = 0; kt < 8; ++kt) {
        int ko = kt * 32;
        __syncthreads();   // previous tile's readers done before overwrite
#pragma unroll
        for (int q = 0; q < 4; ++q) {
            int idx = q * 256 + tid;
            int row = idx >> 3, f4 = idx & 7;
            int slot = f4 ^ ((row >> 1) & 7);
            float4 a = *reinterpret_cast<const float4*>(qf + (size_t)(rb + row) * DIM + ko + f4 * 4);
            *reinterpret_cast<float4*>(As + row * LDST + (slot << 2)) = a;
            float4 b = *reinterpret_cast<const float4*>(sf + (size_t)(cb + row) * DIM + ko + f4 * 4);
            *reinterpret_cast<float4*>(Bs + row * LDST + (slot << 2)) = b;
        }
        __syncthreads();
#pragma unroll
        for (int K = 0; K < 8; ++K) {
            int sA = ((K ^ (ty >> 1)) & 7) << 2;
            int sB = ((K ^ (tx >> 1)) & 7) << 2;
            float4 av[4], bva[4], bvb[4];
            // segment 1: i0-3 x j0-3
#pragma unroll
            for (int i = 0; i < 4; ++i)
                av[i] = *reinterpret_cast<const float4*>(As + (ty + 16 * i) * LDST + sA);
#pragma unroll
            for (int j = 0; j < 4; ++j)
                bva[j] = *reinterpret_cast<const float4*>(Bs + (tx + 16 * j) * LDST + sB);
#pragma unroll
            for (int i = 0; i < 4; ++i)
#pragma unroll
                for (int j = 0; j < 4; ++j) {
                    acc[i][j] += av[i].x * bva[j].x;
                    acc[i][j] += av[i].y * bva[j].y;
                    acc[i][j] += av[i].z * bva[j].z;
                    acc[i][j] += av[i].w * bva[j].w;
                }
            // segment 2: i0-3 x j4-7
#pragma unroll
            for (int j = 0; j < 4; ++j)
                bvb[j] = *reinterpret_cast<const float4*>(Bs + (tx + 16 * (4 + j)) * LDST + sB);
#pragma unroll
            for (int i = 0; i < 4; ++i)
#pragma unroll
                for (int j = 0; j < 4; ++j) {
                    acc[i][4 + j] += av[i].x * bvb[j].x;
                    acc[i][4 + j] += av[i].y * bvb[j].y;
                    acc[i][4 + j] += av[i].z * bvb[j].z;
                    acc[i][4 + j] += av[i].w * bvb[j].w;
                }
            // segment 3: i4-7 x j4-7 (av overwritten)
#pragma unroll
            for (int i = 0; i < 4; ++i)
                av[i] = *reinterpret_cast<const float4*>(As + (ty + 16 * (4 + i)) * LDST + sA);
#pragma unroll
            for (int i = 0; i < 4; ++i)
#pragma unroll
                for (int j = 0; j < 4; ++j) {
                    acc[4 + i][4 + j] += av[i].x * bvb[j].x;
                    acc[4 + i][4 + j] += av[i].y * bvb[j].y;
                    acc[4 + i][4 + j] += av[i].z * bvb[j].z;
                    acc[4 + i][4 + j] += av[i].w * bvb[j].w;
                }
            // segment 4: i4-7 x j0-3 (bva reloaded)
#pragma unroll
            for (int j = 0; j < 4; ++j)
                bva[j] = *reinterpret_cast<const float4*>(Bs + (tx + 16 * j) * LDST + sB);
#pragma unroll
            for (int i = 0; i < 4; ++i)
#pragma unroll
                for (int j = 0; j < 4; ++j) {
                    acc[4 + i][j] += av[i].x * bva[j].x;
                    acc[4 + i][j] += av[i].y * bva[j].y;
                    acc[4 + i][j] += av[i].z * bva[j].z;
                    acc[4 + i][j] += av[i].w * bva[j].w;
                }
        }
    }
    // epilogue: scale, distance, top-3
    {
        float ivb[8], ppc[8];
#pragma unroll
        for (int j = 0; j < 8; ++j) {
            ivb[j] = inv_s[cb + tx + 16 * j];
            ppc[j] = pp[cb + tx + 16 * j];
        }
#pragma unroll
        for (int i = 0; i < 8; ++i) {
            int r = rb + ty + 16 * i;
            float iva = inv_q[r];
            float qqr = qq[r];
#pragma unroll
            for (int j = 0; j < 8; ++j) {
                float dot = acc[i][j] * iva * ivb[j];
                float d2 = qqr + ppc[j] - 2.0f * dot;
                float d = sqrtf(fmaxf(d2, 1e-12f));
                t3ins(t3[i], d);
            }
        }
    }

    // merge per-row top3 across the 16 tx lanes (in-wave butterfly)
#pragma unroll
    for (int off = 1; off < 16; off <<= 1) {
#pragma unroll
        for (int i = 0; i < 8; ++i) {
            float o0 = __shfl_xor(t3[i][0], off, 64);
            float o1 = __shfl_xor(t3[i][1], off, 64);
            float o2 = __shfl_xor(t3[i][2], off, 64);
            t3ins(t3[i], o0);
            t3ins(t3[i], o1);
            t3ins(t3[i], o2);
        }
    }
    if (tx == 0) {
#pragma unroll
        for (int i = 0; i < 8; ++i) {
            float* dst = top3part + ((size_t)cs * Q_ROWS + rb + ty + 16 * i) * 4;
            dst[0] = t3[i][0]; dst[1] = t3[i][1]; dst[2] = t3[i][2]; dst[3] = 0.0f;
        }
    }
}

// ---------------------------------------------------------------------------
// Phase C (R13/R14 proven, ~95-120us): 20 scan steps, one cooperative kernel.
// No serialized RMW chains: per-block slots + per-block release flags,
// wave-parallel poll.
__global__ void iterate_select(const float* __restrict__ qf, const float* __restrict__ inv_q,
                               const float* __restrict__ qq, const float* __restrict__ top3part,
                               float* __restrict__ out, float* __restrict__ bmins,
                               float* __restrict__ candU, int* __restrict__ candI,
                               unsigned* __restrict__ flags) {
    __shared__ float t3s[CR][3];
    __shared__ float invs[CR], qqs[CR], scs[CR];
    __shared__ int kn[CR];
    __shared__ __align__(16) float qfc[DIM];
    __shared__ float red[CT / 64];
    __shared__ float bmin_sh, kth_sh;
    __shared__ int lidx[16];
    __shared__ int lcnt, ccnt;

    int tid = threadIdx.x;
    int bid = blockIdx.x;
    int rbase = bid * CR;
    int lane = tid & 63, wv = tid >> 6;

    if (tid < CR) {
        int r = rbase + tid;
        float b3[3] = {INFINITY, INFINITY, INFINITY};
        for (int csq = 0; csq < COLSPLIT; ++csq) {
            const float* p = top3part + ((size_t)csq * Q_ROWS + r) * 4;
            t3ins(b3, p[0]); t3ins(b3, p[1]); t3ins(b3, p[2]);
        }
        t3s[tid][0] = b3[0]; t3s[tid][1] = b3[1]; t3s[tid][2] = b3[2];
        invs[tid] = inv_q[r];
        qqs[tid] = qq[r];
        kn[tid] = 0;
    }
    __syncthreads();

    for (int t = 0; t <= N_SEL; ++t) {
        if (t > 0) {
            if (tid == 0) lcnt = 0;
            if (wv == 0 && lane < CB) {
                float v = bmins[(t - 1) * CB + lane];
#pragma unroll
                for (int o = 1; o < CB; o <<= 1) v = fminf(v, __shfl_xor(v, o, 64));
                if (lane == 0) kth_sh = v;
            }
            __syncthreads();
            float kth = kth_sh;
            if (tid < CB * SLOTS) {
                float u = candU[(t - 1) * CB * SLOTS + tid];
                if (u <= kth) {
                    int p = atomicAdd(&lcnt, 1);
                    if (p < 16) lidx[p] = candI[(t - 1) * CB * SLOTS + tid];
                }
            }
            __syncthreads();
            int m = lcnt < 16 ? lcnt : 16;
            for (int j = 0; j < m; ++j) {
                int c = lidx[j];
                if (tid == 0 && c >= rbase && c < rbase + CR) kn[c - rbase] = 1;
                if (tid < DIM) qfc[tid] = qf[(size_t)c * DIM + tid] * inv_q[c];
                __syncthreads();
                float qqc = qq[c];
                int row = tid >> 2, sub = tid & 3;
                const float4* rp = reinterpret_cast<const float4*>(qf + (size_t)(rbase + row) * DIM);
                const float4* cp = reinterpret_cast<const float4*>(qfc);
                float si = invs[row];
                float d = 0.0f;
#pragma unroll
                for (int i2 = 0; i2 < 16; ++i2) {
                    float4 v = rp[sub + 4 * i2];
                    float4 w = cp[sub + 4 * i2];
                    d += (v.x * si) * w.x;
                    d += (v.y * si) * w.y;
                    d += (v.z * si) * w.z;
                    d += (v.w * si) * w.w;
                }
                d += __shfl_xor(d, 1, 64);
                d += __shfl_xor(d, 2, 64);
                if (sub == 0) {
                    float d2 = qqs[row] + qqc - 2.0f * d;
                    float dist = sqrtf(fmaxf(d2, 1e-12f));
                    float b3[3] = {t3s[row][0], t3s[row][1], t3s[row][2]};
                    t3ins(b3, dist);
                    t3s[row][0] = b3[0]; t3s[row][1] = b3[1]; t3s[row][2] = b3[2];
                }
                __syncthreads();
            }
            __syncthreads();
        }

        if (t == N_SEL) {
            if (tid < CR)
                out[rbase + tid] = 1.0f - smean3(t3s[tid][0], t3s[tid][1], t3s[tid][2]);
            return;
        }

        if (tid == 0) ccnt = 0;
        if (tid < CR)
            scs[tid] = kn[tid] ? INFINITY : smean3(t3s[tid][0], t3s[tid][1], t3s[tid][2]);
        __syncthreads();

        float mn = (tid < CR) ? scs[tid] : INFINITY;
#pragma unroll
        for (int o = 1; o < 64; o <<= 1) mn = fminf(mn, __shfl_xor(mn, o, 64));
        if (lane == 0) red[wv] = mn;
        __syncthreads();
        if (tid == 0) {
            float v = red[0];
#pragma unroll
            for (int i = 1; i < CT / 64; ++i) v = fminf(v, red[i]);
            bmin_sh = v;
            bmins[t * CB + bid] = v;
        }
        __syncthreads();
        float bmin = bmin_sh;
        if (tid < CR && scs[tid] == bmin) {
            int p = atomicAdd(&ccnt, 1);
            if (p < SLOTS) {
                candU[t * CB * SLOTS + bid * SLOTS + p] = scs[tid];
                candI[t * CB * SLOTS + bid * SLOTS + p] = rbase + tid;
            }
        }
        __syncthreads();
        if (tid == 0) {
            for (int p = ccnt; p < SLOTS; ++p) {
                candU[t * CB * SLOTS + bid * SLOTS + p] = INFINITY;
                candI[t * CB * SLOTS + bid * SLOTS + p] = 0;
            }
            __hip_atomic_store(&flags[t * CB + bid], 1u,
                               __ATOMIC_RELEASE, __HIP_MEMORY_SCOPE_AGENT);
        }
        if (wv == 0) {
            for (;;) {
                bool ok = (lane >= CB) ||
                          (__hip_atomic_load(&flags[t * CB + lane],
                                             __ATOMIC_RELAXED, __HIP_MEMORY_SCOPE_AGENT) != 0u);
                if (__all(ok)) break;
                __builtin_amdgcn_s_sleep(1);
            }
            __threadfence();
        }
        __syncthreads();
    }
}

// ---------------------------------------------------------------------------
extern "C" void kernel_launch(void* const* d_in, const int* in_sizes, int n_in,
                              void* d_out, int out_size, void* d_ws, size_t ws_size,
                              hipStream_t stream) {
    const float* sfeat = (const float*)d_in[0];
    const float* qfeat = (const float*)d_in[2];
    float* out = (float*)d_out;

    float* ws = (float*)d_ws;
    float* inv_q = ws + WS_INV_Q;
    float* qq    = ws + WS_QQ;
    float* inv_s = ws + WS_INV_S;
    float* pp    = ws + WS_PP;
    float* top3p = ws + WS_TOP3P;
    float* bmins = ws + WS_BMIN;
    float* candU = ws + WS_CANDU;
    int* candI   = (int*)(ws + WS_CANDI);
    unsigned* flags = (unsigned*)(ws + WS_FLAGS);

    int n_extra = out_size - Q_ROWS;
    if (n_extra < 0) n_extra = 0;

    norm_rows<<<Q_ROWS * 64 / 256, 256, 0, stream>>>(qfeat, inv_q, qq, Q_ROWS);
    norm_rows<<<S_ROWS * 64 / 256, 256, 0, stream>>>(sfeat, inv_s, pp, S_ROWS);
    init_ws<<<32, 256, 0, stream>>>(flags, out, n_extra);   // 8192 threads >= max(32*CB, n_extra)
    knn_support_kernel<<<64 * COLSPLIT, 256, 0, stream>>>(qfeat, sfeat, inv_q, inv_s, qq, pp, top3p);

    const float* a0 = qfeat; const float* a1 = inv_q; const float* a2 = qq;
    const float* a3 = top3p; float* a4 = out;
    float* a5 = bmins; float* a6 = candU; int* a7 = candI; unsigned* a8 = flags;
    void* cargs[] = {&a0, &a1, &a2, &a3, &a4, &a5, &a6, &a7, &a8};
    hipLaunchCooperativeKernel(iterate_select, dim3(CB), dim3(CT), cargs, 0, stream);
}

// Round 17
// 302.710 us; speedup vs baseline: 2.1530x; 1.5554x over previous
//
#include <hip/hip_runtime.h>
#include <hip/hip_bf16.h>

// Problem constants (fixed by reference setup_inputs)
#define S_ROWS 4096
#define Q_ROWS 8192
#define DIM 256
#define N_SEL 19       // selection events (20 scan steps)
#define COLSPLIT 32    // phase-B column splits (128 cols per block)
#define BM 128         // phase-B rows per block
#define LDSU 40        // phase-B LDS row stride (ushorts): 80B, frag reads 2-way-free
#define CB 32          // phase-C blocks
#define CT 1024        // phase-C threads per block
#define CR 256         // phase-C rows per block (4 threads per row)
#define SLOTS 4        // candidate slots per block per iteration

typedef __attribute__((ext_vector_type(8))) short bf16x8;
typedef __attribute__((ext_vector_type(4))) float f32x4;

// Workspace layout (floats)
#define WS_INV_Q 0
#define WS_QQ    (WS_INV_Q + Q_ROWS)
#define WS_INV_S (WS_QQ + Q_ROWS)
#define WS_PP    (WS_INV_S + S_ROWS)
#define WS_TOP3P (WS_PP + S_ROWS)                    // [COLSPLIT][Q_ROWS][4]
#define WS_BMIN  (WS_TOP3P + COLSPLIT * Q_ROWS * 4)  // [32][CB]
#define WS_CANDU (WS_BMIN + 32 * CB)                 // [32][CB*SLOTS]
#define WS_CANDI (WS_CANDU + 32 * CB * SLOTS)        // [32][CB*SLOTS] (int)
#define WS_FLAGS (WS_CANDI + 32 * CB * SLOTS)        // unsigned [32*CB] barrier flags

// ---------------------------------------------------------------------------
__global__ void norm_rows(const float* __restrict__ x, float* __restrict__ inv,
                          float* __restrict__ ssq, int nrows) {
    int w = (blockIdx.x * blockDim.x + threadIdx.x) >> 6;
    int lane = threadIdx.x & 63;
    if (w >= nrows) return;
    float4 v = reinterpret_cast<const float4*>(x + (size_t)w * DIM)[lane];
    float s = v.x * v.x + v.y * v.y + v.z * v.z + v.w * v.w;
#pragma unroll
    for (int o = 1; o < 64; o <<= 1) s += __shfl_xor(s, o, 64);
    float invn = 1.0f / sqrtf(s);
    float t = v.x * invn; float u = t * t;
    t = v.y * invn; u += t * t;
    t = v.z * invn; u += t * t;
    t = v.w * invn; u += t * t;
#pragma unroll
    for (int o = 1; o < 64; o <<= 1) u += __shfl_xor(u, o, 64);
    if (lane == 0) { inv[w] = invn; ssq[w] = u; }
}

// ---------------------------------------------------------------------------
// MUST be launched with >= max(32*CB, n_extra) threads (R12 bug).
__global__ void init_ws(unsigned* __restrict__ flags, float* __restrict__ out, int n_extra) {
    int t = blockIdx.x * blockDim.x + threadIdx.x;
    if (t < 32 * CB) flags[t] = 0u;
    if (t < n_extra) out[Q_ROWS + t] = 1.0f;
}

// ---------------------------------------------------------------------------
__device__ __forceinline__ void t3ins(float (&t3)[3], float d) {
    float mx = fmaxf(fmaxf(t3[0], t3[1]), t3[2]);
    if (d < mx) {
        if (t3[0] == mx) t3[0] = d;
        else if (t3[1] == mx) t3[1] = d;
        else t3[2] = d;
    }
}

__device__ __forceinline__ float smean3(float a, float b, float c) {
    float lo = fminf(fminf(a, b), c);
    float hi = fmaxf(fmaxf(a, b), c);
    float md = fminf(fmaxf(a, b), fminf(fmaxf(b, c), fmaxf(a, c)));
    return ((lo + md) + hi) * (1.0f / 3.0f);
}

__device__ __forceinline__ unsigned short f2bf(float x) {   // RNE fp32 -> bf16
    unsigned u = __float_as_uint(x);
    return (unsigned short)((u + 0x7FFFu + ((u >> 16) & 1u)) >> 16);
}
__device__ __forceinline__ float bf2f(unsigned short h) {
    return __uint_as_float(((unsigned)h) << 16);
}

// ---------------------------------------------------------------------------
// Phase B: split-precision bf16 MFMA GEMM + per-row top-3.
// dot = Ahi*Bhi + Ahi*Blo + Alo*Bhi (3x mfma_f32_16x16x32_bf16; lo*lo dropped,
// err ~3e-7 << observed selection min-gaps, which survived fp32 reorders R2/R7).
// Staging: proven full-line fp32 global loads (R5 lesson), convert to hi/lo
// ONCE per element during staging, LDS stride 40 ushort (fragment ds_read_b128
// 2-way = free). Fragment map (16x16x32): lane l holds row/col l&15,
// k = (l>>4)*8 + e; C/D: col = lane&15, row = (lane>>4)*4 + reg [m89].
// Per wave per kt: 20 ds_read_b128 + 48 MFMA (vs fp32 path: 160 reads + 2048
// v_fmac) — removes the LDS-issue-pipe bottleneck that capped fp32 at 306us.
__launch_bounds__(256, 2)
__global__ void knn_support_kernel(const float* __restrict__ qf, const float* __restrict__ sf,
                                   const float* __restrict__ inv_q, const float* __restrict__ inv_s,
                                   const float* __restrict__ qq, const float* __restrict__ pp,
                                   float* __restrict__ top3part) {
    __shared__ __align__(16) unsigned short Ah[BM * LDSU];
    __shared__ __align__(16) unsigned short Al[BM * LDSU];
    __shared__ __align__(16) unsigned short Bh[BM * LDSU];
    __shared__ __align__(16) unsigned short Bl[BM * LDSU];

    int b0 = blockIdx.x;
    int rb = (b0 & 63) * BM;
    int cs = b0 >> 6;            // 0..31
    int cb = cs * 128;
    int tid = threadIdx.x;
    int lane = tid & 63, wv = tid >> 6;
    int g = lane >> 4, c0l = lane & 15;

    f32x4 acc[2][8];
#pragma unroll
    for (int rt = 0; rt < 2; ++rt)
#pragma unroll
        for (int ct = 0; ct < 8; ++ct) acc[rt][ct] = (f32x4){0.f, 0.f, 0.f, 0.f};

    for (int kt = 0; kt < 8; ++kt) {
        int ko = kt * 32;
        __syncthreads();   // previous tile's readers done before overwrite
#pragma unroll
        for (int q = 0; q < 4; ++q) {
            int idx = q * 256 + tid;
            int row = idx >> 3, f4 = idx & 7;
            float4 a = *reinterpret_cast<const float4*>(qf + (size_t)(rb + row) * DIM + ko + f4 * 4);
            float4 b = *reinterpret_cast<const float4*>(sf + (size_t)(cb + row) * DIM + ko + f4 * 4);
            ushort4 ah, al, bh, bl;
            ah.x = f2bf(a.x); al.x = f2bf(a.x - bf2f(ah.x));
            ah.y = f2bf(a.y); al.y = f2bf(a.y - bf2f(ah.y));
            ah.z = f2bf(a.z); al.z = f2bf(a.z - bf2f(ah.z));
            ah.w = f2bf(a.w); al.w = f2bf(a.w - bf2f(ah.w));
            bh.x = f2bf(b.x); bl.x = f2bf(b.x - bf2f(bh.x));
            bh.y = f2bf(b.y); bl.y = f2bf(b.y - bf2f(bh.y));
            bh.z = f2bf(b.z); bl.z = f2bf(b.z - bf2f(bh.z));
            bh.w = f2bf(b.w); bl.w = f2bf(b.w - bf2f(bh.w));
            *reinterpret_cast<ushort4*>(Ah + row * LDSU + f4 * 4) = ah;
            *reinterpret_cast<ushort4*>(Al + row * LDSU + f4 * 4) = al;
            *reinterpret_cast<ushort4*>(Bh + row * LDSU + f4 * 4) = bh;
            *reinterpret_cast<ushort4*>(Bl + row * LDSU + f4 * 4) = bl;
        }
        __syncthreads();
        // A fragments for this wave's 2 row-tiles (rows wv*32 + rt*16 + c0l)
        bf16x8 ahi[2], alo[2];
#pragma unroll
        for (int rt = 0; rt < 2; ++rt) {
            int arow = wv * 32 + rt * 16 + c0l;
            ahi[rt] = *reinterpret_cast<const bf16x8*>(Ah + arow * LDSU + g * 8);
            alo[rt] = *reinterpret_cast<const bf16x8*>(Al + arow * LDSU + g * 8);
        }
#pragma unroll
        for (int ct = 0; ct < 8; ++ct) {
            int brow = ct * 16 + c0l;
            bf16x8 bhi = *reinterpret_cast<const bf16x8*>(Bh + brow * LDSU + g * 8);
            bf16x8 blo = *reinterpret_cast<const bf16x8*>(Bl + brow * LDSU + g * 8);
#pragma unroll
            for (int rt = 0; rt < 2; ++rt) {
                acc[rt][ct] = __builtin_amdgcn_mfma_f32_16x16x32_bf16(ahi[rt], bhi, acc[rt][ct], 0, 0, 0);
                acc[rt][ct] = __builtin_amdgcn_mfma_f32_16x16x32_bf16(ahi[rt], blo, acc[rt][ct], 0, 0, 0);
                acc[rt][ct] = __builtin_amdgcn_mfma_f32_16x16x32_bf16(alo[rt], bhi, acc[rt][ct], 0, 0, 0);
            }
        }
    }

    // epilogue: scale, distance, per-row top-3 (C layout: col=c0l, row=g*4+v)
    float ivb[8], ppc[8];
#pragma unroll
    for (int ct = 0; ct < 8; ++ct) {
        ivb[ct] = inv_s[cb + ct * 16 + c0l];
        ppc[ct] = pp[cb + ct * 16 + c0l];
    }
    float t3r[2][4][3];
#pragma unroll
    for (int rt = 0; rt < 2; ++rt)
#pragma unroll
        for (int v = 0; v < 4; ++v)
            t3r[rt][v][0] = t3r[rt][v][1] = t3r[rt][v][2] = INFINITY;
#pragma unroll
    for (int rt = 0; rt < 2; ++rt) {
        float iva[4], qqr[4];
#pragma unroll
        for (int v = 0; v < 4; ++v) {
            int row = rb + wv * 32 + rt * 16 + g * 4 + v;
            iva[v] = inv_q[row];
            qqr[v] = qq[row];
        }
#pragma unroll
        for (int ct = 0; ct < 8; ++ct) {
#pragma unroll
            for (int v = 0; v < 4; ++v) {
                float dot = acc[rt][ct][v] * iva[v] * ivb[ct];
                float d2 = qqr[v] + ppc[ct] - 2.0f * dot;
                float d = sqrtf(fmaxf(d2, 1e-12f));
                t3ins(t3r[rt][v], d);
            }
        }
    }
    // merge across the 16 lanes sharing each row (c0l varies, g fixed)
#pragma unroll
    for (int off = 1; off < 16; off <<= 1) {
#pragma unroll
        for (int rt = 0; rt < 2; ++rt)
#pragma unroll
            for (int v = 0; v < 4; ++v) {
                float o0 = __shfl_xor(t3r[rt][v][0], off, 64);
                float o1 = __shfl_xor(t3r[rt][v][1], off, 64);
                float o2 = __shfl_xor(t3r[rt][v][2], off, 64);
                t3ins(t3r[rt][v], o0);
                t3ins(t3r[rt][v], o1);
                t3ins(t3r[rt][v], o2);
            }
    }
    if (c0l == 0) {
#pragma unroll
        for (int rt = 0; rt < 2; ++rt)
#pragma unroll
            for (int v = 0; v < 4; ++v) {
                int row = rb + wv * 32 + rt * 16 + g * 4 + v;
                float* dst = top3part + ((size_t)cs * Q_ROWS + row) * 4;
                dst[0] = t3r[rt][v][0]; dst[1] = t3r[rt][v][1];
                dst[2] = t3r[rt][v][2]; dst[3] = 0.0f;
            }
    }
}

// ---------------------------------------------------------------------------
// Phase C (R13/R16 proven, ~110us): 20 scan steps, one cooperative kernel.
// No serialized RMW chains: per-block slots + per-block release flags,
// wave-parallel poll.
__global__ void iterate_select(const float* __restrict__ qf, const float* __restrict__ inv_q,
                               const float* __restrict__ qq, const float* __restrict__ top3part,
                               float* __restrict__ out, float* __restrict__ bmins,
                               float* __restrict__ candU, int* __restrict__ candI,
                               unsigned* __restrict__ flags) {
    __shared__ float t3s[CR][3];
    __shared__ float invs[CR], qqs[CR], scs[CR];
    __shared__ int kn[CR];
    __shared__ __align__(16) float qfc[DIM];
    __shared__ float red[CT / 64];
    __shared__ float bmin_sh, kth_sh;
    __shared__ int lidx[16];
    __shared__ int lcnt, ccnt;

    int tid = threadIdx.x;
    int bid = blockIdx.x;
    int rbase = bid * CR;
    int lane = tid & 63, wv = tid >> 6;

    if (tid < CR) {
        int r = rbase + tid;
        float b3[3] = {INFINITY, INFINITY, INFINITY};
        for (int csq = 0; csq < COLSPLIT; ++csq) {
            const float* p = top3part + ((size_t)csq * Q_ROWS + r) * 4;
            t3ins(b3, p[0]); t3ins(b3, p[1]); t3ins(b3, p[2]);
        }
        t3s[tid][0] = b3[0]; t3s[tid][1] = b3[1]; t3s[tid][2] = b3[2];
        invs[tid] = inv_q[r];
        qqs[tid] = qq[r];
        kn[tid] = 0;
    }
    __syncthreads();

    for (int t = 0; t <= N_SEL; ++t) {
        if (t > 0) {
            if (tid == 0) lcnt = 0;
            if (wv == 0 && lane < CB) {
                float v = bmins[(t - 1) * CB + lane];
#pragma unroll
                for (int o = 1; o < CB; o <<= 1) v = fminf(v, __shfl_xor(v, o, 64));
                if (lane == 0) kth_sh = v;
            }
            __syncthreads();
            float kth = kth_sh;
            if (tid < CB * SLOTS) {
                float u = candU[(t - 1) * CB * SLOTS + tid];
                if (u <= kth) {
                    int p = atomicAdd(&lcnt, 1);
                    if (p < 16) lidx[p] = candI[(t - 1) * CB * SLOTS + tid];
                }
            }
            __syncthreads();
            int m = lcnt < 16 ? lcnt : 16;
            for (int j = 0; j < m; ++j) {
                int c = lidx[j];
                if (tid == 0 && c >= rbase && c < rbase + CR) kn[c - rbase] = 1;
                if (tid < DIM) qfc[tid] = qf[(size_t)c * DIM + tid] * inv_q[c];
                __syncthreads();
                float qqc = qq[c];
                int row = tid >> 2, sub = tid & 3;
                const float4* rp = reinterpret_cast<const float4*>(qf + (size_t)(rbase + row) * DIM);
                const float4* cp = reinterpret_cast<const float4*>(qfc);
                float si = invs[row];
                float d = 0.0f;
#pragma unroll
                for (int i2 = 0; i2 < 16; ++i2) {
                    float4 v = rp[sub + 4 * i2];
                    float4 w = cp[sub + 4 * i2];
                    d += (v.x * si) * w.x;
                    d += (v.y * si) * w.y;
                    d += (v.z * si) * w.z;
                    d += (v.w * si) * w.w;
                }
                d += __shfl_xor(d, 1, 64);
                d += __shfl_xor(d, 2, 64);
                if (sub == 0) {
                    float d2 = qqs[row] + qqc - 2.0f * d;
                    float dist = sqrtf(fmaxf(d2, 1e-12f));
                    float b3[3] = {t3s[row][0], t3s[row][1], t3s[row][2]};
                    t3ins(b3, dist);
                    t3s[row][0] = b3[0]; t3s[row][1] = b3[1]; t3s[row][2] = b3[2];
                }
                __syncthreads();
            }
            __syncthreads();
        }

        if (t == N_SEL) {
            if (tid < CR)
                out[rbase + tid] = 1.0f - smean3(t3s[tid][0], t3s[tid][1], t3s[tid][2]);
            return;
        }

        if (tid == 0) ccnt = 0;
        if (tid < CR)
            scs[tid] = kn[tid] ? INFINITY : smean3(t3s[tid][0], t3s[tid][1], t3s[tid][2]);
        __syncthreads();

        float mn = (tid < CR) ? scs[tid] : INFINITY;
#pragma unroll
        for (int o = 1; o < 64; o <<= 1) mn = fminf(mn, __shfl_xor(mn, o, 64));
        if (lane == 0) red[wv] = mn;
        __syncthreads();
        if (tid == 0) {
            float v = red[0];
#pragma unroll
            for (int i = 1; i < CT / 64; ++i) v = fminf(v, red[i]);
            bmin_sh = v;
            bmins[t * CB + bid] = v;
        }
        __syncthreads();
        float bmin = bmin_sh;
        if (tid < CR && scs[tid] == bmin) {
            int p = atomicAdd(&ccnt, 1);
            if (p < SLOTS) {
                candU[t * CB * SLOTS + bid * SLOTS + p] = scs[tid];
                candI[t * CB * SLOTS + bid * SLOTS + p] = rbase + tid;
            }
        }
        __syncthreads();
        if (tid == 0) {
            for (int p = ccnt; p < SLOTS; ++p) {
                candU[t * CB * SLOTS + bid * SLOTS + p] = INFINITY;
                candI[t * CB * SLOTS + bid * SLOTS + p] = 0;
            }
            __hip_atomic_store(&flags[t * CB + bid], 1u,
                               __ATOMIC_RELEASE, __HIP_MEMORY_SCOPE_AGENT);
        }
        if (wv == 0) {
            for (;;) {
                bool ok = (lane >= CB) ||
                          (__hip_atomic_load(&flags[t * CB + lane],
                                             __ATOMIC_RELAXED, __HIP_MEMORY_SCOPE_AGENT) != 0u);
                if (__all(ok)) break;
                __builtin_amdgcn_s_sleep(1);
            }
            __threadfence();
        }
        __syncthreads();
    }
}

// ---------------------------------------------------------------------------
extern "C" void kernel_launch(void* const* d_in, const int* in_sizes, int n_in,
                              void* d_out, int out_size, void* d_ws, size_t ws_size,
                              hipStream_t stream) {
    const float* sfeat = (const float*)d_in[0];
    const float* qfeat = (const float*)d_in[2];
    float* out = (float*)d_out;

    float* ws = (float*)d_ws;
    float* inv_q = ws + WS_INV_Q;
    float* qq    = ws + WS_QQ;
    float* inv_s = ws + WS_INV_S;
    float* pp    = ws + WS_PP;
    float* top3p = ws + WS_TOP3P;
    float* bmins = ws + WS_BMIN;
    float* candU = ws + WS_CANDU;
    int* candI   = (int*)(ws + WS_CANDI);
    unsigned* flags = (unsigned*)(ws + WS_FLAGS);

    int n_extra = out_size - Q_ROWS;
    if (n_extra < 0) n_extra = 0;

    norm_rows<<<Q_ROWS * 64 / 256, 256, 0, stream>>>(qfeat, inv_q, qq, Q_ROWS);
    norm_rows<<<S_ROWS * 64 / 256, 256, 0, stream>>>(sfeat, inv_s, pp, S_ROWS);
    init_ws<<<32, 256, 0, stream>>>(flags, out, n_extra);   // 8192 threads >= max(32*CB, n_extra)
    knn_support_kernel<<<64 * COLSPLIT, 256, 0, stream>>>(qfeat, sfeat, inv_q, inv_s, qq, pp, top3p);

    const float* a0 = qfeat; const float* a1 = inv_q; const float* a2 = qq;
    const float* a3 = top3p; float* a4 = out;
    float* a5 = bmins; float* a6 = candU; int* a7 = candI; unsigned* a8 = flags;
    void* cargs[] = {&a0, &a1, &a2, &a3, &a4, &a5, &a6, &a7, &a8};
    hipLaunchCooperativeKernel(iterate_select, dim3(CB), dim3(CT), cargs, 0, stream);
}

// Round 18
// 283.650 us; speedup vs baseline: 2.2976x; 1.0672x over previous
//
#include <hip/hip_runtime.h>
#include <hip/hip_bf16.h>

// Problem constants (fixed by reference setup_inputs)
#define S_ROWS 4096
#define Q_ROWS 8192
#define DIM 256
#define N_SEL 19       // selection events (20 scan steps)
#define COLSPLIT 32    // phase-B column splits (128 cols per block)
#define BM 128         // phase-B rows per block
#define LDSU 40        // phase-B LDS row stride (ushorts)
#define CB 32          // phase-C blocks
#define CT 1024        // phase-C threads per block
#define CR 256         // phase-C rows per block (4 threads per row)
#define SLOTS 4        // candidate slots per block per iteration

typedef __attribute__((ext_vector_type(8))) short bf16x8;
typedef __attribute__((ext_vector_type(4))) float f32x4;

// Workspace layout (floats)
#define WS_INV_Q 0
#define WS_QQ    (WS_INV_Q + Q_ROWS)
#define WS_INV_S (WS_QQ + Q_ROWS)
#define WS_PP    (WS_INV_S + S_ROWS)
#define WS_TOP3P (WS_PP + S_ROWS)                    // [COLSPLIT][Q_ROWS][4]
#define WS_CANDU (WS_TOP3P + COLSPLIT * Q_ROWS * 4)  // [32][CB*SLOTS]
#define WS_CANDI (WS_CANDU + 32 * CB * SLOTS)        // [32][CB*SLOTS] (int)
#define WS_PACKED (WS_CANDI + 32 * CB * SLOTS)       // uint64 [32*CB] (even float offset)

// ---------------------------------------------------------------------------
__global__ void norm_rows(const float* __restrict__ x, float* __restrict__ inv,
                          float* __restrict__ ssq, int nrows) {
    int w = (blockIdx.x * blockDim.x + threadIdx.x) >> 6;
    int lane = threadIdx.x & 63;
    if (w >= nrows) return;
    float4 v = reinterpret_cast<const float4*>(x + (size_t)w * DIM)[lane];
    float s = v.x * v.x + v.y * v.y + v.z * v.z + v.w * v.w;
#pragma unroll
    for (int o = 1; o < 64; o <<= 1) s += __shfl_xor(s, o, 64);
    float invn = 1.0f / sqrtf(s);
    float t = v.x * invn; float u = t * t;
    t = v.y * invn; u += t * t;
    t = v.z * invn; u += t * t;
    t = v.w * invn; u += t * t;
#pragma unroll
    for (int o = 1; o < 64; o <<= 1) u += __shfl_xor(u, o, 64);
    if (lane == 0) { inv[w] = invn; ssq[w] = u; }
}

// ---------------------------------------------------------------------------
// MUST cover >= max(32*CB, n_extra) threads (R12 bug). Sentinel-inits packed
// every launch -> graph replays are race-free (poll only passes on THIS
// launch's release stores).
__global__ void init_ws(unsigned long long* __restrict__ packed,
                        float* __restrict__ out, int n_extra) {
    int t = blockIdx.x * blockDim.x + threadIdx.x;
    if (t < 32 * CB) packed[t] = ~0ull;
    if (t < n_extra) out[Q_ROWS + t] = 1.0f;
}

// ---------------------------------------------------------------------------
__device__ __forceinline__ void t3ins(float (&t3)[3], float d) {
    float mx = fmaxf(fmaxf(t3[0], t3[1]), t3[2]);
    if (d < mx) {
        if (t3[0] == mx) t3[0] = d;
        else if (t3[1] == mx) t3[1] = d;
        else t3[2] = d;
    }
}

__device__ __forceinline__ float smean3(float a, float b, float c) {
    float lo = fminf(fminf(a, b), c);
    float hi = fmaxf(fmaxf(a, b), c);
    float md = fminf(fmaxf(a, b), fminf(fmaxf(b, c), fmaxf(a, c)));
    return ((lo + md) + hi) * (1.0f / 3.0f);
}

__device__ __forceinline__ unsigned short f2bf(float x) {   // RNE fp32 -> bf16
    unsigned u = __float_as_uint(x);
    return (unsigned short)((u + 0x7FFFu + ((u >> 16) & 1u)) >> 16);
}
__device__ __forceinline__ float bf2f(unsigned short h) {
    return __uint_as_float(((unsigned)h) << 16);
}

// ---------------------------------------------------------------------------
// Phase B (R17 proven, ~105us, absmax 0.0): split-precision bf16 MFMA GEMM,
// dot = Ahi*Bhi + Ahi*Blo + Alo*Bhi (lo*lo dropped, err ~3e-7 — vanishes at
// bf16 output granularity; zero selection flips measured). Full-line fp32
// staging with hi/lo conversion once per element; 20 ds_read_b128 + 48 MFMA
// per wave per kt (vs fp32 path's 160 reads + 2048 fmac).
__launch_bounds__(256, 2)
__global__ void knn_support_kernel(const float* __restrict__ qf, const float* __restrict__ sf,
                                   const float* __restrict__ inv_q, const float* __restrict__ inv_s,
                                   const float* __restrict__ qq, const float* __restrict__ pp,
                                   float* __restrict__ top3part) {
    __shared__ __align__(16) unsigned short Ah[BM * LDSU];
    __shared__ __align__(16) unsigned short Al[BM * LDSU];
    __shared__ __align__(16) unsigned short Bh[BM * LDSU];
    __shared__ __align__(16) unsigned short Bl[BM * LDSU];

    int b0 = blockIdx.x;
    int rb = (b0 & 63) * BM;
    int cs = b0 >> 6;            // 0..31
    int cb = cs * 128;
    int tid = threadIdx.x;
    int lane = tid & 63, wv = tid >> 6;
    int g = lane >> 4, c0l = lane & 15;

    f32x4 acc[2][8];
#pragma unroll
    for (int rt = 0; rt < 2; ++rt)
#pragma unroll
        for (int ct = 0; ct < 8; ++ct) acc[rt][ct] = (f32x4){0.f, 0.f, 0.f, 0.f};

    for (int kt = 0; kt < 8; ++kt) {
        int ko = kt * 32;
        __syncthreads();
#pragma unroll
        for (int q = 0; q < 4; ++q) {
            int idx = q * 256 + tid;
            int row = idx >> 3, f4 = idx & 7;
            float4 a = *reinterpret_cast<const float4*>(qf + (size_t)(rb + row) * DIM + ko + f4 * 4);
            float4 b = *reinterpret_cast<const float4*>(sf + (size_t)(cb + row) * DIM + ko + f4 * 4);
            ushort4 ah, al, bh, bl;
            ah.x = f2bf(a.x); al.x = f2bf(a.x - bf2f(ah.x));
            ah.y = f2bf(a.y); al.y = f2bf(a.y - bf2f(ah.y));
            ah.z = f2bf(a.z); al.z = f2bf(a.z - bf2f(ah.z));
            ah.w = f2bf(a.w); al.w = f2bf(a.w - bf2f(ah.w));
            bh.x = f2bf(b.x); bl.x = f2bf(b.x - bf2f(bh.x));
            bh.y = f2bf(b.y); bl.y = f2bf(b.y - bf2f(bh.y));
            bh.z = f2bf(b.z); bl.z = f2bf(b.z - bf2f(bh.z));
            bh.w = f2bf(b.w); bl.w = f2bf(b.w - bf2f(bh.w));
            *reinterpret_cast<ushort4*>(Ah + row * LDSU + f4 * 4) = ah;
            *reinterpret_cast<ushort4*>(Al + row * LDSU + f4 * 4) = al;
            *reinterpret_cast<ushort4*>(Bh + row * LDSU + f4 * 4) = bh;
            *reinterpret_cast<ushort4*>(Bl + row * LDSU + f4 * 4) = bl;
        }
        __syncthreads();
        bf16x8 ahi[2], alo[2];
#pragma unroll
        for (int rt = 0; rt < 2; ++rt) {
            int arow = wv * 32 + rt * 16 + c0l;
            ahi[rt] = *reinterpret_cast<const bf16x8*>(Ah + arow * LDSU + g * 8);
            alo[rt] = *reinterpret_cast<const bf16x8*>(Al + arow * LDSU + g * 8);
        }
#pragma unroll
        for (int ct = 0; ct < 8; ++ct) {
            int brow = ct * 16 + c0l;
            bf16x8 bhi = *reinterpret_cast<const bf16x8*>(Bh + brow * LDSU + g * 8);
            bf16x8 blo = *reinterpret_cast<const bf16x8*>(Bl + brow * LDSU + g * 8);
#pragma unroll
            for (int rt = 0; rt < 2; ++rt) {
                acc[rt][ct] = __builtin_amdgcn_mfma_f32_16x16x32_bf16(ahi[rt], bhi, acc[rt][ct], 0, 0, 0);
                acc[rt][ct] = __builtin_amdgcn_mfma_f32_16x16x32_bf16(ahi[rt], blo, acc[rt][ct], 0, 0, 0);
                acc[rt][ct] = __builtin_amdgcn_mfma_f32_16x16x32_bf16(alo[rt], bhi, acc[rt][ct], 0, 0, 0);
            }
        }
    }

    // epilogue: scale, distance, per-row top-3 (C layout: col=c0l, row=g*4+v)
    float ivb[8], ppc[8];
#pragma unroll
    for (int ct = 0; ct < 8; ++ct) {
        ivb[ct] = inv_s[cb + ct * 16 + c0l];
        ppc[ct] = pp[cb + ct * 16 + c0l];
    }
    float t3r[2][4][3];
#pragma unroll
    for (int rt = 0; rt < 2; ++rt)
#pragma unroll
        for (int v = 0; v < 4; ++v)
            t3r[rt][v][0] = t3r[rt][v][1] = t3r[rt][v][2] = INFINITY;
#pragma unroll
    for (int rt = 0; rt < 2; ++rt) {
        float iva[4], qqr[4];
#pragma unroll
        for (int v = 0; v < 4; ++v) {
            int row = rb + wv * 32 + rt * 16 + g * 4 + v;
            iva[v] = inv_q[row];
            qqr[v] = qq[row];
        }
#pragma unroll
        for (int ct = 0; ct < 8; ++ct) {
#pragma unroll
            for (int v = 0; v < 4; ++v) {
                float dot = acc[rt][ct][v] * iva[v] * ivb[ct];
                float d2 = qqr[v] + ppc[ct] - 2.0f * dot;
                float d = sqrtf(fmaxf(d2, 1e-12f));
                t3ins(t3r[rt][v], d);
            }
        }
    }
#pragma unroll
    for (int off = 1; off < 16; off <<= 1) {
#pragma unroll
        for (int rt = 0; rt < 2; ++rt)
#pragma unroll
            for (int v = 0; v < 4; ++v) {
                float o0 = __shfl_xor(t3r[rt][v][0], off, 64);
                float o1 = __shfl_xor(t3r[rt][v][1], off, 64);
                float o2 = __shfl_xor(t3r[rt][v][2], off, 64);
                t3ins(t3r[rt][v], o0);
                t3ins(t3r[rt][v], o1);
                t3ins(t3r[rt][v], o2);
            }
    }
    if (c0l == 0) {
#pragma unroll
        for (int rt = 0; rt < 2; ++rt)
#pragma unroll
            for (int v = 0; v < 4; ++v) {
                int row = rb + wv * 32 + rt * 16 + g * 4 + v;
                float* dst = top3part + ((size_t)cs * Q_ROWS + row) * 4;
                dst[0] = t3r[rt][v][0]; dst[1] = t3r[rt][v][1];
                dst[2] = t3r[rt][v][2]; dst[3] = 0.0f;
            }
    }
}

// ---------------------------------------------------------------------------
// Phase C: 20 scan steps, one cooperative kernel. ONE packed uint64 per block
// per iteration = {bmin_bits:32 | cand_idx:13<<1 | multi:1}; the packed word
// is simultaneously the barrier flag (sentinel ~0ull), the block-min (integer
// min over high words is float min: scores positive), and the candidate (no
// second read round in the common 1-candidate case). Multi-tie blocks set
// bit 0; consumer reads their 4 pre-published slots (release/acquire-ordered).
__global__ void iterate_select(const float* __restrict__ qf, const float* __restrict__ inv_q,
                               const float* __restrict__ qq, const float* __restrict__ top3part,
                               float* __restrict__ out, float* __restrict__ candU,
                               int* __restrict__ candI, unsigned long long* __restrict__ packed) {
    __shared__ float t3s[CR][3];
    __shared__ float invs[CR], qqs[CR], scs[CR];
    __shared__ int kn[CR];
    __shared__ __align__(16) float qfc[DIM];
    __shared__ float red[CT / 64];
    __shared__ float bmin_sh;
    __shared__ unsigned long long pk_sh[CB];
    __shared__ int lidx[16];
    __shared__ int lidx_loc[SLOTS];
    __shared__ int lcnt, ccnt;

    int tid = threadIdx.x;
    int bid = blockIdx.x;
    int rbase = bid * CR;
    int lane = tid & 63, wv = tid >> 6;

    if (tid < CR) {
        int r = rbase + tid;
        float b3[3] = {INFINITY, INFINITY, INFINITY};
        for (int csq = 0; csq < COLSPLIT; ++csq) {
            const float* p = top3part + ((size_t)csq * Q_ROWS + r) * 4;
            t3ins(b3, p[0]); t3ins(b3, p[1]); t3ins(b3, p[2]);
        }
        t3s[tid][0] = b3[0]; t3s[tid][1] = b3[1]; t3s[tid][2] = b3[2];
        invs[tid] = inv_q[r];
        qqs[tid] = qq[r];
        kn[tid] = 0;
    }
    __syncthreads();

    for (int t = 0; t <= N_SEL; ++t) {
        if (t > 0) {
            // pk_sh[] holds iteration t-1's packed words (filled by the poll)
            if (tid == 0) lcnt = 0;
            __syncthreads();
            if (wv == 0) {
                unsigned long long pv = (lane < CB) ? pk_sh[lane] : ~0ull;
                unsigned bb = (lane < CB) ? (unsigned)(pv >> 32) : 0xFFFFFFFFu;
                unsigned mb = bb;
#pragma unroll
                for (int o = 1; o < 64; o <<= 1) mb = min(mb, (unsigned)__shfl_xor((int)mb, o, 64));
                if (lane < CB && bb == mb) {
                    if (!(pv & 1ull)) {
                        int p = atomicAdd(&lcnt, 1);
                        if (p < 16) lidx[p] = (int)((pv >> 1) & 0x7FFFull);
                    } else {
                        for (int s2 = 0; s2 < SLOTS; ++s2) {
                            float u = candU[(t - 1) * CB * SLOTS + lane * SLOTS + s2];
                            if (__float_as_uint(u) == mb) {
                                int p = atomicAdd(&lcnt, 1);
                                if (p < 16) lidx[p] = candI[(t - 1) * CB * SLOTS + lane * SLOTS + s2];
                            }
                        }
                    }
                }
            }
            __syncthreads();
            int m = lcnt < 16 ? lcnt : 16;
            for (int j = 0; j < m; ++j) {
                int c = lidx[j];
                if (tid == 0 && c >= rbase && c < rbase + CR) kn[c - rbase] = 1;
                if (tid < DIM) qfc[tid] = qf[(size_t)c * DIM + tid] * inv_q[c];
                __syncthreads();
                float qqc = qq[c];
                int row = tid >> 2, sub = tid & 3;
                const float4* rp = reinterpret_cast<const float4*>(qf + (size_t)(rbase + row) * DIM);
                const float4* cp = reinterpret_cast<const float4*>(qfc);
                float si = invs[row];
                float d = 0.0f;
#pragma unroll
                for (int i2 = 0; i2 < 16; ++i2) {
                    float4 v = rp[sub + 4 * i2];
                    float4 w = cp[sub + 4 * i2];
                    d += (v.x * si) * w.x;
                    d += (v.y * si) * w.y;
                    d += (v.z * si) * w.z;
                    d += (v.w * si) * w.w;
                }
                d += __shfl_xor(d, 1, 64);
                d += __shfl_xor(d, 2, 64);
                if (sub == 0) {
                    float d2 = qqs[row] + qqc - 2.0f * d;
                    float dist = sqrtf(fmaxf(d2, 1e-12f));
                    float b3[3] = {t3s[row][0], t3s[row][1], t3s[row][2]};
                    t3ins(b3, dist);
                    t3s[row][0] = b3[0]; t3s[row][1] = b3[1]; t3s[row][2] = b3[2];
                }
                __syncthreads();
            }
            __syncthreads();
        }

        if (t == N_SEL) {
            if (tid < CR)
                out[rbase + tid] = 1.0f - smean3(t3s[tid][0], t3s[tid][1], t3s[tid][2]);
            return;
        }

        // scores (inf = known)
        if (tid == 0) ccnt = 0;
        if (tid < CR)
            scs[tid] = kn[tid] ? INFINITY : smean3(t3s[tid][0], t3s[tid][1], t3s[tid][2]);
        __syncthreads();

        // block min
        float mn = (tid < CR) ? scs[tid] : INFINITY;
#pragma unroll
        for (int o = 1; o < 64; o <<= 1) mn = fminf(mn, __shfl_xor(mn, o, 64));
        if (lane == 0) red[wv] = mn;
        __syncthreads();
        if (tid == 0) {
            float v = red[0];
#pragma unroll
            for (int i = 1; i < CT / 64; ++i) v = fminf(v, red[i]);
            bmin_sh = v;
        }
        __syncthreads();
        float bmin = bmin_sh;
        // publish block-min ties into slots (LDS-atomic ordering; bmin==inf
        // degenerate case is skipped by consumers since kth stays finite)
        if (tid < CR && scs[tid] == bmin) {
            int p = atomicAdd(&ccnt, 1);
            if (p < SLOTS) {
                candU[t * CB * SLOTS + bid * SLOTS + p] = scs[tid];
                candI[t * CB * SLOTS + bid * SLOTS + p] = rbase + tid;
                lidx_loc[p] = rbase + tid;
            }
        }
        __syncthreads();
        if (tid == 0) {
            for (int p = ccnt; p < SLOTS; ++p) {
                candU[t * CB * SLOTS + bid * SLOTS + p] = INFINITY;
                candI[t * CB * SLOTS + bid * SLOTS + p] = 0;
            }
            unsigned long long pk = ((unsigned long long)__float_as_uint(bmin) << 32)
                                  | ((unsigned long long)(unsigned)lidx_loc[0] << 1)
                                  | (ccnt > 1 ? 1ull : 0ull);
            __hip_atomic_store(&packed[t * CB + bid], pk,
                               __ATOMIC_RELEASE, __HIP_MEMORY_SCOPE_AGENT);
        }
        // barrier == poll packed[t] into LDS (flag and data in one round trip)
        if (wv == 0) {
            for (;;) {
                unsigned long long pv = (lane < CB)
                    ? __hip_atomic_load(&packed[t * CB + lane], __ATOMIC_RELAXED, __HIP_MEMORY_SCOPE_AGENT)
                    : 0ull;
                bool ok = (lane >= CB) || (pv != ~0ull);
                if (__all(ok)) { if (lane < CB) pk_sh[lane] = pv; break; }
                __builtin_amdgcn_s_sleep(1);
            }
            __threadfence();
        }
        __syncthreads();
    }
}

// ---------------------------------------------------------------------------
extern "C" void kernel_launch(void* const* d_in, const int* in_sizes, int n_in,
                              void* d_out, int out_size, void* d_ws, size_t ws_size,
                              hipStream_t stream) {
    const float* sfeat = (const float*)d_in[0];
    const float* qfeat = (const float*)d_in[2];
    float* out = (float*)d_out;

    float* ws = (float*)d_ws;
    float* inv_q = ws + WS_INV_Q;
    float* qq    = ws + WS_QQ;
    float* inv_s = ws + WS_INV_S;
    float* pp    = ws + WS_PP;
    float* top3p = ws + WS_TOP3P;
    float* candU = ws + WS_CANDU;
    int* candI   = (int*)(ws + WS_CANDI);
    unsigned long long* packed = (unsigned long long*)(ws + WS_PACKED);

    int n_extra = out_size - Q_ROWS;
    if (n_extra < 0) n_extra = 0;

    norm_rows<<<Q_ROWS * 64 / 256, 256, 0, stream>>>(qfeat, inv_q, qq, Q_ROWS);
    norm_rows<<<S_ROWS * 64 / 256, 256, 0, stream>>>(sfeat, inv_s, pp, S_ROWS);
    init_ws<<<32, 256, 0, stream>>>(packed, out, n_extra);  // 8192 threads >= max(32*CB, n_extra)
    knn_support_kernel<<<64 * COLSPLIT, 256, 0, stream>>>(qfeat, sfeat, inv_q, inv_s, qq, pp, top3p);

    const float* a0 = qfeat; const float* a1 = inv_q; const float* a2 = qq;
    const float* a3 = top3p; float* a4 = out;
    float* a5 = candU; int* a6 = candI; unsigned long long* a7 = packed;
    void* cargs[] = {&a0, &a1, &a2, &a3, &a4, &a5, &a6, &a7};
    hipLaunchCooperativeKernel(iterate_select, dim3(CB), dim3(CT), cargs, 0, stream);
}

// Round 19
// 248.870 us; speedup vs baseline: 2.6187x; 1.1398x over previous
//
#include <hip/hip_runtime.h>
#include <hip/hip_bf16.h>

// Problem constants (fixed by reference setup_inputs)
#define S_ROWS 4096
#define Q_ROWS 8192
#define DIM 256
#define N_SEL 19       // selection events (20 scan steps)
#define COLSPLIT 32    // phase-B column splits (128 cols per block)
#define BM 128         // phase-B rows per block
#define LDSU 40        // phase-B LDS row stride (ushorts)
#define CB 32          // phase-C blocks
#define CT 1024        // phase-C threads per block
#define CR 256         // phase-C rows per block (4 threads per row)
#define SLOTS 4        // candidate slots per block per iteration
#define PKS 16         // packed-word stride in uint64 = 128B: one cache line per
                       // block -> release-stores don't false-share (R18 lesson)

typedef __attribute__((ext_vector_type(8))) short bf16x8;
typedef __attribute__((ext_vector_type(4))) float f32x4;

// Workspace layout (floats)
#define WS_INV_Q 0
#define WS_QQ    (WS_INV_Q + Q_ROWS)
#define WS_INV_S (WS_QQ + Q_ROWS)
#define WS_PP    (WS_INV_S + S_ROWS)
#define WS_TOP3P (WS_PP + S_ROWS)                    // [COLSPLIT][Q_ROWS][4]
#define WS_CANDU (WS_TOP3P + COLSPLIT * Q_ROWS * 4)  // [32][CB*SLOTS]
#define WS_CANDI (WS_CANDU + 32 * CB * SLOTS)        // [32][CB*SLOTS] (int)
#define WS_PACKED (WS_CANDI + 32 * CB * SLOTS)       // uint64 [32*CB*PKS]

// ---------------------------------------------------------------------------
// Row L2-norms for BOTH inputs in one launch (saves a launch gap).
__global__ void norm_rows_all(const float* __restrict__ qf, const float* __restrict__ sf,
                              float* __restrict__ inv_q, float* __restrict__ qq,
                              float* __restrict__ inv_s, float* __restrict__ pp) {
    int w = (blockIdx.x * blockDim.x + threadIdx.x) >> 6;
    int lane = threadIdx.x & 63;
    if (w >= Q_ROWS + S_ROWS) return;
    const float* x;
    float *inv, *ssq;
    if (w < Q_ROWS) { x = qf + (size_t)w * DIM; inv = inv_q + w; ssq = qq + w; }
    else { int v2 = w - Q_ROWS; x = sf + (size_t)v2 * DIM; inv = inv_s + v2; ssq = pp + v2; }
    float4 v = reinterpret_cast<const float4*>(x)[lane];
    float s = v.x * v.x + v.y * v.y + v.z * v.z + v.w * v.w;
#pragma unroll
    for (int o = 1; o < 64; o <<= 1) s += __shfl_xor(s, o, 64);
    float invn = 1.0f / sqrtf(s);
    float t = v.x * invn; float u = t * t;
    t = v.y * invn; u += t * t;
    t = v.z * invn; u += t * t;
    t = v.w * invn; u += t * t;
#pragma unroll
    for (int o = 1; o < 64; o <<= 1) u += __shfl_xor(u, o, 64);
    if (lane == 0) { *inv = invn; *ssq = u; }
}

// ---------------------------------------------------------------------------
// MUST cover >= max(32*CB, n_extra) threads (R12 bug). Sentinel-inits packed
// every launch -> graph replays race-free.
__global__ void init_ws(unsigned long long* __restrict__ packed,
                        float* __restrict__ out, int n_extra) {
    int t = blockIdx.x * blockDim.x + threadIdx.x;
    if (t < 32 * CB) packed[t * PKS] = ~0ull;
    if (t < n_extra) out[Q_ROWS + t] = 1.0f;
}

// ---------------------------------------------------------------------------
__device__ __forceinline__ void t3ins(float (&t3)[3], float d) {
    float mx = fmaxf(fmaxf(t3[0], t3[1]), t3[2]);
    if (d < mx) {
        if (t3[0] == mx) t3[0] = d;
        else if (t3[1] == mx) t3[1] = d;
        else t3[2] = d;
    }
}

__device__ __forceinline__ float smean3(float a, float b, float c) {
    float lo = fminf(fminf(a, b), c);
    float hi = fmaxf(fmaxf(a, b), c);
    float md = fminf(fmaxf(a, b), fminf(fmaxf(b, c), fmaxf(a, c)));
    return ((lo + md) + hi) * (1.0f / 3.0f);
}

// RNE pair conversions (same rounding as R18's manual bit-twiddle, but the
// compiler emits v_cvt_pk_bf16_f32 — ~3x fewer VALU ops in staging).
__device__ __forceinline__ unsigned pk_hi(float x, float y, float& rx, float& ry) {
    __hip_bfloat162 h = __float22bfloat162_rn(make_float2(x, y));
    float2 f = __bfloat1622float2(h);
    rx = x - f.x; ry = y - f.y;
    return *reinterpret_cast<unsigned*>(&h);
}
__device__ __forceinline__ unsigned pk_rn(float x, float y) {
    __hip_bfloat162 h = __float22bfloat162_rn(make_float2(x, y));
    return *reinterpret_cast<unsigned*>(&h);
}

// ---------------------------------------------------------------------------
// Phase B (R17/R18 proven structure, absmax 0.0): split-precision bf16 MFMA,
// dot = Ahi*Bhi + Ahi*Blo + Alo*Bhi. Staging conversion now via cvt_pk pairs.
__launch_bounds__(256, 2)
__global__ void knn_support_kernel(const float* __restrict__ qf, const float* __restrict__ sf,
                                   const float* __restrict__ inv_q, const float* __restrict__ inv_s,
                                   const float* __restrict__ qq, const float* __restrict__ pp,
                                   float* __restrict__ top3part) {
    __shared__ __align__(16) unsigned short Ah[BM * LDSU];
    __shared__ __align__(16) unsigned short Al[BM * LDSU];
    __shared__ __align__(16) unsigned short Bh[BM * LDSU];
    __shared__ __align__(16) unsigned short Bl[BM * LDSU];

    int b0 = blockIdx.x;
    int rb = (b0 & 63) * BM;
    int cs = b0 >> 6;            // 0..31
    int cb = cs * 128;
    int tid = threadIdx.x;
    int lane = tid & 63, wv = tid >> 6;
    int g = lane >> 4, c0l = lane & 15;

    f32x4 acc[2][8];
#pragma unroll
    for (int rt = 0; rt < 2; ++rt)
#pragma unroll
        for (int ct = 0; ct < 8; ++ct) acc[rt][ct] = (f32x4){0.f, 0.f, 0.f, 0.f};

    for (int kt = 0; kt < 8; ++kt) {
        int ko = kt * 32;
        __syncthreads();
#pragma unroll
        for (int q = 0; q < 4; ++q) {
            int idx = q * 256 + tid;
            int row = idx >> 3, f4 = idx & 7;
            float4 a = *reinterpret_cast<const float4*>(qf + (size_t)(rb + row) * DIM + ko + f4 * 4);
            float4 b = *reinterpret_cast<const float4*>(sf + (size_t)(cb + row) * DIM + ko + f4 * 4);
            float r0, r1, r2, r3;
            unsigned ah0 = pk_hi(a.x, a.y, r0, r1), ah1 = pk_hi(a.z, a.w, r2, r3);
            unsigned al0 = pk_rn(r0, r1), al1 = pk_rn(r2, r3);
            unsigned bh0 = pk_hi(b.x, b.y, r0, r1), bh1 = pk_hi(b.z, b.w, r2, r3);
            unsigned bl0 = pk_rn(r0, r1), bl1 = pk_rn(r2, r3);
            *reinterpret_cast<uint2*>(Ah + row * LDSU + f4 * 4) = make_uint2(ah0, ah1);
            *reinterpret_cast<uint2*>(Al + row * LDSU + f4 * 4) = make_uint2(al0, al1);
            *reinterpret_cast<uint2*>(Bh + row * LDSU + f4 * 4) = make_uint2(bh0, bh1);
            *reinterpret_cast<uint2*>(Bl + row * LDSU + f4 * 4) = make_uint2(bl0, bl1);
        }
        __syncthreads();
        bf16x8 ahi[2], alo[2];
#pragma unroll
        for (int rt = 0; rt < 2; ++rt) {
            int arow = wv * 32 + rt * 16 + c0l;
            ahi[rt] = *reinterpret_cast<const bf16x8*>(Ah + arow * LDSU + g * 8);
            alo[rt] = *reinterpret_cast<const bf16x8*>(Al + arow * LDSU + g * 8);
        }
#pragma unroll
        for (int ct = 0; ct < 8; ++ct) {
            int brow = ct * 16 + c0l;
            bf16x8 bhi = *reinterpret_cast<const bf16x8*>(Bh + brow * LDSU + g * 8);
            bf16x8 blo = *reinterpret_cast<const bf16x8*>(Bl + brow * LDSU + g * 8);
#pragma unroll
            for (int rt = 0; rt < 2; ++rt) {
                acc[rt][ct] = __builtin_amdgcn_mfma_f32_16x16x32_bf16(ahi[rt], bhi, acc[rt][ct], 0, 0, 0);
                acc[rt][ct] = __builtin_amdgcn_mfma_f32_16x16x32_bf16(ahi[rt], blo, acc[rt][ct], 0, 0, 0);
                acc[rt][ct] = __builtin_amdgcn_mfma_f32_16x16x32_bf16(alo[rt], bhi, acc[rt][ct], 0, 0, 0);
            }
        }
    }

    // epilogue: scale, distance, per-row top-3 (C layout: col=c0l, row=g*4+v)
    float ivb[8], ppc[8];
#pragma unroll
    for (int ct = 0; ct < 8; ++ct) {
        ivb[ct] = inv_s[cb + ct * 16 + c0l];
        ppc[ct] = pp[cb + ct * 16 + c0l];
    }
    float t3r[2][4][3];
#pragma unroll
    for (int rt = 0; rt < 2; ++rt)
#pragma unroll
        for (int v = 0; v < 4; ++v)
            t3r[rt][v][0] = t3r[rt][v][1] = t3r[rt][v][2] = INFINITY;
#pragma unroll
    for (int rt = 0; rt < 2; ++rt) {
        float iva[4], qqr[4];
#pragma unroll
        for (int v = 0; v < 4; ++v) {
            int row = rb + wv * 32 + rt * 16 + g * 4 + v;
            iva[v] = inv_q[row];
            qqr[v] = qq[row];
        }
#pragma unroll
        for (int ct = 0; ct < 8; ++ct) {
#pragma unroll
            for (int v = 0; v < 4; ++v) {
                float dot = acc[rt][ct][v] * iva[v] * ivb[ct];
                float d2 = qqr[v] + ppc[ct] - 2.0f * dot;
                float d = sqrtf(fmaxf(d2, 1e-12f));
                t3ins(t3r[rt][v], d);
            }
        }
    }
#pragma unroll
    for (int off = 1; off < 16; off <<= 1) {
#pragma unroll
        for (int rt = 0; rt < 2; ++rt)
#pragma unroll
            for (int v = 0; v < 4; ++v) {
                float o0 = __shfl_xor(t3r[rt][v][0], off, 64);
                float o1 = __shfl_xor(t3r[rt][v][1], off, 64);
                float o2 = __shfl_xor(t3r[rt][v][2], off, 64);
                t3ins(t3r[rt][v], o0);
                t3ins(t3r[rt][v], o1);
                t3ins(t3r[rt][v], o2);
            }
    }
    if (c0l == 0) {
#pragma unroll
        for (int rt = 0; rt < 2; ++rt)
#pragma unroll
            for (int v = 0; v < 4; ++v) {
                int row = rb + wv * 32 + rt * 16 + g * 4 + v;
                float* dst = top3part + ((size_t)cs * Q_ROWS + row) * 4;
                dst[0] = t3r[rt][v][0]; dst[1] = t3r[rt][v][1];
                dst[2] = t3r[rt][v][2]; dst[3] = 0.0f;
            }
    }
}

// ---------------------------------------------------------------------------
// Phase C: 20 scan steps, one cooperative kernel. One packed uint64 per block
// per iteration = {bmin_bits:32 | cand_idx:13<<1 | multi:1}, now padded to a
// PRIVATE 128B line per block (stride PKS): release-stores land on distinct
// lines in parallel instead of ping-ponging 2 shared lines across 8 XCDs.
__global__ void iterate_select(const float* __restrict__ qf, const float* __restrict__ inv_q,
                               const float* __restrict__ qq, const float* __restrict__ top3part,
                               float* __restrict__ out, float* __restrict__ candU,
                               int* __restrict__ candI, unsigned long long* __restrict__ packed) {
    __shared__ float t3s[CR][3];
    __shared__ float invs[CR], qqs[CR], scs[CR];
    __shared__ int kn[CR];
    __shared__ __align__(16) float qfc[DIM];
    __shared__ float red[CT / 64];
    __shared__ float bmin_sh;
    __shared__ unsigned long long pk_sh[CB];
    __shared__ int lidx[16];
    __shared__ int lidx_loc[SLOTS];
    __shared__ int lcnt, ccnt;

    int tid = threadIdx.x;
    int bid = blockIdx.x;
    int rbase = bid * CR;
    int lane = tid & 63, wv = tid >> 6;

    if (tid < CR) {
        int r = rbase + tid;
        float b3[3] = {INFINITY, INFINITY, INFINITY};
        for (int csq = 0; csq < COLSPLIT; ++csq) {
            const float* p = top3part + ((size_t)csq * Q_ROWS + r) * 4;
            t3ins(b3, p[0]); t3ins(b3, p[1]); t3ins(b3, p[2]);
        }
        t3s[tid][0] = b3[0]; t3s[tid][1] = b3[1]; t3s[tid][2] = b3[2];
        invs[tid] = inv_q[r];
        qqs[tid] = qq[r];
        kn[tid] = 0;
    }
    __syncthreads();

    for (int t = 0; t <= N_SEL; ++t) {
        if (t > 0) {
            if (tid == 0) lcnt = 0;
            __syncthreads();
            if (wv == 0) {
                unsigned long long pv = (lane < CB) ? pk_sh[lane] : ~0ull;
                unsigned bb = (lane < CB) ? (unsigned)(pv >> 32) : 0xFFFFFFFFu;
                unsigned mb = bb;
#pragma unroll
                for (int o = 1; o < 64; o <<= 1) mb = min(mb, (unsigned)__shfl_xor((int)mb, o, 64));
                if (lane < CB && bb == mb) {
                    if (!(pv & 1ull)) {
                        int p = atomicAdd(&lcnt, 1);
                        if (p < 16) lidx[p] = (int)((pv >> 1) & 0x7FFFull);
                    } else {
                        for (int s2 = 0; s2 < SLOTS; ++s2) {
                            float u = candU[(t - 1) * CB * SLOTS + lane * SLOTS + s2];
                            if (__float_as_uint(u) == mb) {
                                int p = atomicAdd(&lcnt, 1);
                                if (p < 16) lidx[p] = candI[(t - 1) * CB * SLOTS + lane * SLOTS + s2];
                            }
                        }
                    }
                }
            }
            __syncthreads();
            int m = lcnt < 16 ? lcnt : 16;
            for (int j = 0; j < m; ++j) {
                int c = lidx[j];
                if (tid == 0 && c >= rbase && c < rbase + CR) kn[c - rbase] = 1;
                if (tid < 64) {
                    float4 v = reinterpret_cast<const float4*>(qf + (size_t)c * DIM)[tid];
                    float s = inv_q[c];
                    reinterpret_cast<float4*>(qfc)[tid] = make_float4(v.x * s, v.y * s, v.z * s, v.w * s);
                }
                __syncthreads();
                float qqc = qq[c];
                int row = tid >> 2, sub = tid & 3;
                const float4* rp = reinterpret_cast<const float4*>(qf + (size_t)(rbase + row) * DIM);
                const float4* cp = reinterpret_cast<const float4*>(qfc);
                float si = invs[row];
                float d = 0.0f;
#pragma unroll
                for (int i2 = 0; i2 < 16; ++i2) {
                    float4 v = rp[sub + 4 * i2];
                    float4 w = cp[sub + 4 * i2];
                    d += (v.x * si) * w.x;
                    d += (v.y * si) * w.y;
                    d += (v.z * si) * w.z;
                    d += (v.w * si) * w.w;
                }
                d += __shfl_xor(d, 1, 64);
                d += __shfl_xor(d, 2, 64);
                if (sub == 0) {
                    float d2 = qqs[row] + qqc - 2.0f * d;
                    float dist = sqrtf(fmaxf(d2, 1e-12f));
                    float b3[3] = {t3s[row][0], t3s[row][1], t3s[row][2]};
                    t3ins(b3, dist);
                    t3s[row][0] = b3[0]; t3s[row][1] = b3[1]; t3s[row][2] = b3[2];
                }
                __syncthreads();
            }
            __syncthreads();
        }

        if (t == N_SEL) {
            if (tid < CR)
                out[rbase + tid] = 1.0f - smean3(t3s[tid][0], t3s[tid][1], t3s[tid][2]);
            return;
        }

        // scores (inf = known)
        if (tid == 0) ccnt = 0;
        if (tid < CR)
            scs[tid] = kn[tid] ? INFINITY : smean3(t3s[tid][0], t3s[tid][1], t3s[tid][2]);
        __syncthreads();

        // block min
        float mn = (tid < CR) ? scs[tid] : INFINITY;
#pragma unroll
        for (int o = 1; o < 64; o <<= 1) mn = fminf(mn, __shfl_xor(mn, o, 64));
        if (lane == 0) red[wv] = mn;
        __syncthreads();
        if (tid == 0) {
            float v = red[0];
#pragma unroll
            for (int i = 1; i < CT / 64; ++i) v = fminf(v, red[i]);
            bmin_sh = v;
        }
        __syncthreads();
        float bmin = bmin_sh;
        if (tid < CR && scs[tid] == bmin) {
            int p = atomicAdd(&ccnt, 1);
            if (p < SLOTS) {
                candU[t * CB * SLOTS + bid * SLOTS + p] = scs[tid];
                candI[t * CB * SLOTS + bid * SLOTS + p] = rbase + tid;
                lidx_loc[p] = rbase + tid;
            }
        }
        __syncthreads();
        if (tid == 0) {
            for (int p = ccnt; p < SLOTS; ++p) {
                candU[t * CB * SLOTS + bid * SLOTS + p] = INFINITY;
                candI[t * CB * SLOTS + bid * SLOTS + p] = 0;
            }
            unsigned long long pk = ((unsigned long long)__float_as_uint(bmin) << 32)
                                  | ((unsigned long long)(unsigned)lidx_loc[0] << 1)
                                  | (ccnt > 1 ? 1ull : 0ull);
            __hip_atomic_store(&packed[(t * CB + bid) * PKS], pk,
                               __ATOMIC_RELEASE, __HIP_MEMORY_SCOPE_AGENT);
        }
        // barrier == poll packed[t] into LDS (flag and data in one round trip)
        if (wv == 0) {
            for (;;) {
                unsigned long long pv = (lane < CB)
                    ? __hip_atomic_load(&packed[(t * CB + lane) * PKS], __ATOMIC_RELAXED, __HIP_MEMORY_SCOPE_AGENT)
                    : 0ull;
                bool ok = (lane >= CB) || (pv != ~0ull);
                if (__all(ok)) { if (lane < CB) pk_sh[lane] = pv; break; }
                __builtin_amdgcn_s_sleep(1);
            }
            __threadfence();
        }
        __syncthreads();
    }
}

// ---------------------------------------------------------------------------
extern "C" void kernel_launch(void* const* d_in, const int* in_sizes, int n_in,
                              void* d_out, int out_size, void* d_ws, size_t ws_size,
                              hipStream_t stream) {
    const float* sfeat = (const float*)d_in[0];
    const float* qfeat = (const float*)d_in[2];
    float* out = (float*)d_out;

    float* ws = (float*)d_ws;
    float* inv_q = ws + WS_INV_Q;
    float* qq    = ws + WS_QQ;
    float* inv_s = ws + WS_INV_S;
    float* pp    = ws + WS_PP;
    float* top3p = ws + WS_TOP3P;
    float* candU = ws + WS_CANDU;
    int* candI   = (int*)(ws + WS_CANDI);
    unsigned long long* packed = (unsigned long long*)(ws + WS_PACKED);

    int n_extra = out_size - Q_ROWS;
    if (n_extra < 0) n_extra = 0;

    norm_rows_all<<<(Q_ROWS + S_ROWS) * 64 / 256, 256, 0, stream>>>(qfeat, sfeat, inv_q, qq, inv_s, pp);
    init_ws<<<32, 256, 0, stream>>>(packed, out, n_extra);  // 8192 threads >= max(32*CB, n_extra)
    knn_support_kernel<<<64 * COLSPLIT, 256, 0, stream>>>(qfeat, sfeat, inv_q, inv_s, qq, pp, top3p);

    const float* a0 = qfeat; const float* a1 = inv_q; const float* a2 = qq;
    const float* a3 = top3p; float* a4 = out;
    float* a5 = candU; int* a6 = candI; unsigned long long* a7 = packed;
    void* cargs[] = {&a0, &a1, &a2, &a3, &a4, &a5, &a6, &a7};
    hipLaunchCooperativeKernel(iterate_select, dim3(CB), dim3(CT), cargs, 0, stream);
}

// Round 20
// 225.091 us; speedup vs baseline: 2.8954x; 1.1056x over previous
//
#include <hip/hip_runtime.h>
#include <hip/hip_bf16.h>

// Problem constants (fixed by reference setup_inputs)
#define S_ROWS 4096
#define Q_ROWS 8192
#define DIM 256
#define N_SEL 19       // selection events (20 scan steps)
#define COLSPLIT 32    // phase-B column splits (128 cols per block)
#define BM 128         // phase-B rows per block
#define LDSU 40        // phase-B LDS row stride (ushorts)
#define CB 32          // phase-C blocks
#define CT 1024        // phase-C threads per block
#define CR 256         // phase-C rows per block (4 threads per row)
#define SLOTS 4        // candidate slots per block per iteration
#define PKS 16         // packed-word stride in uint64 = 128B/line (R18 lesson)

typedef __attribute__((ext_vector_type(8))) short bf16x8;
typedef __attribute__((ext_vector_type(4))) float f32x4;

// Workspace layout (floats)
#define WS_INV_Q 0
#define WS_QQ    (WS_INV_Q + Q_ROWS)
#define WS_INV_S (WS_QQ + Q_ROWS)
#define WS_PP    (WS_INV_S + S_ROWS)
#define WS_TOP3P (WS_PP + S_ROWS)                    // [COLSPLIT][Q_ROWS][4]
#define WS_CANDU (WS_TOP3P + COLSPLIT * Q_ROWS * 4)  // [32][CB*SLOTS]
#define WS_CANDI (WS_CANDU + 32 * CB * SLOTS)        // [32][CB*SLOTS] (int)
#define WS_PACKED (WS_CANDI + 32 * CB * SLOTS)       // uint64 [32*CB*PKS]

// ---------------------------------------------------------------------------
// Row L2-norms for BOTH inputs in one launch.
__global__ void norm_rows_all(const float* __restrict__ qf, const float* __restrict__ sf,
                              float* __restrict__ inv_q, float* __restrict__ qq,
                              float* __restrict__ inv_s, float* __restrict__ pp) {
    int w = (blockIdx.x * blockDim.x + threadIdx.x) >> 6;
    int lane = threadIdx.x & 63;
    if (w >= Q_ROWS + S_ROWS) return;
    const float* x;
    float *inv, *ssq;
    if (w < Q_ROWS) { x = qf + (size_t)w * DIM; inv = inv_q + w; ssq = qq + w; }
    else { int v2 = w - Q_ROWS; x = sf + (size_t)v2 * DIM; inv = inv_s + v2; ssq = pp + v2; }
    float4 v = reinterpret_cast<const float4*>(x)[lane];
    float s = v.x * v.x + v.y * v.y + v.z * v.z + v.w * v.w;
#pragma unroll
    for (int o = 1; o < 64; o <<= 1) s += __shfl_xor(s, o, 64);
    float invn = 1.0f / sqrtf(s);
    float t = v.x * invn; float u = t * t;
    t = v.y * invn; u += t * t;
    t = v.z * invn; u += t * t;
    t = v.w * invn; u += t * t;
#pragma unroll
    for (int o = 1; o < 64; o <<= 1) u += __shfl_xor(u, o, 64);
    if (lane == 0) { *inv = invn; *ssq = u; }
}

// ---------------------------------------------------------------------------
// MUST cover >= max(32*CB, n_extra) threads (R12 bug).
__global__ void init_ws(unsigned long long* __restrict__ packed,
                        float* __restrict__ out, int n_extra) {
    int t = blockIdx.x * blockDim.x + threadIdx.x;
    if (t < 32 * CB) packed[t * PKS] = ~0ull;
    if (t < n_extra) out[Q_ROWS + t] = 1.0f;
}

// ---------------------------------------------------------------------------
__device__ __forceinline__ void t3ins(float (&t3)[3], float d) {
    float mx = fmaxf(fmaxf(t3[0], t3[1]), t3[2]);
    if (d < mx) {
        if (t3[0] == mx) t3[0] = d;
        else if (t3[1] == mx) t3[1] = d;
        else t3[2] = d;
    }
}

__device__ __forceinline__ float smean3(float a, float b, float c) {
    float lo = fminf(fminf(a, b), c);
    float hi = fmaxf(fmaxf(a, b), c);
    float md = fminf(fmaxf(a, b), fminf(fmaxf(b, c), fmaxf(a, c)));
    return ((lo + md) + hi) * (1.0f / 3.0f);
}

// RNE pair conversions -> v_cvt_pk_bf16_f32 (R19, same rounding as manual RNE).
__device__ __forceinline__ unsigned pk_hi(float x, float y, float& rx, float& ry) {
    __hip_bfloat162 h = __float22bfloat162_rn(make_float2(x, y));
    float2 f = __bfloat1622float2(h);
    rx = x - f.x; ry = y - f.y;
    return *reinterpret_cast<unsigned*>(&h);
}
__device__ __forceinline__ unsigned pk_rn(float x, float y) {
    __hip_bfloat162 h = __float22bfloat162_rn(make_float2(x, y));
    return *reinterpret_cast<unsigned*>(&h);
}

// ---------------------------------------------------------------------------
// Phase B (R17-R19 proven, ~80us, absmax 0.0): split-precision bf16 MFMA,
// dot = Ahi*Bhi + Ahi*Blo + Alo*Bhi. FROZEN.
__launch_bounds__(256, 2)
__global__ void knn_support_kernel(const float* __restrict__ qf, const float* __restrict__ sf,
                                   const float* __restrict__ inv_q, const float* __restrict__ inv_s,
                                   const float* __restrict__ qq, const float* __restrict__ pp,
                                   float* __restrict__ top3part) {
    __shared__ __align__(16) unsigned short Ah[BM * LDSU];
    __shared__ __align__(16) unsigned short Al[BM * LDSU];
    __shared__ __align__(16) unsigned short Bh[BM * LDSU];
    __shared__ __align__(16) unsigned short Bl[BM * LDSU];

    int b0 = blockIdx.x;
    int rb = (b0 & 63) * BM;
    int cs = b0 >> 6;            // 0..31
    int cb = cs * 128;
    int tid = threadIdx.x;
    int lane = tid & 63, wv = tid >> 6;
    int g = lane >> 4, c0l = lane & 15;

    f32x4 acc[2][8];
#pragma unroll
    for (int rt = 0; rt < 2; ++rt)
#pragma unroll
        for (int ct = 0; ct < 8; ++ct) acc[rt][ct] = (f32x4){0.f, 0.f, 0.f, 0.f};

    for (int kt = 0; kt < 8; ++kt) {
        int ko = kt * 32;
        __syncthreads();
#pragma unroll
        for (int q = 0; q < 4; ++q) {
            int idx = q * 256 + tid;
            int row = idx >> 3, f4 = idx & 7;
            float4 a = *reinterpret_cast<const float4*>(qf + (size_t)(rb + row) * DIM + ko + f4 * 4);
            float4 b = *reinterpret_cast<const float4*>(sf + (size_t)(cb + row) * DIM + ko + f4 * 4);
            float r0, r1, r2, r3;
            unsigned ah0 = pk_hi(a.x, a.y, r0, r1), ah1 = pk_hi(a.z, a.w, r2, r3);
            unsigned al0 = pk_rn(r0, r1), al1 = pk_rn(r2, r3);
            unsigned bh0 = pk_hi(b.x, b.y, r0, r1), bh1 = pk_hi(b.z, b.w, r2, r3);
            unsigned bl0 = pk_rn(r0, r1), bl1 = pk_rn(r2, r3);
            *reinterpret_cast<uint2*>(Ah + row * LDSU + f4 * 4) = make_uint2(ah0, ah1);
            *reinterpret_cast<uint2*>(Al + row * LDSU + f4 * 4) = make_uint2(al0, al1);
            *reinterpret_cast<uint2*>(Bh + row * LDSU + f4 * 4) = make_uint2(bh0, bh1);
            *reinterpret_cast<uint2*>(Bl + row * LDSU + f4 * 4) = make_uint2(bl0, bl1);
        }
        __syncthreads();
        bf16x8 ahi[2], alo[2];
#pragma unroll
        for (int rt = 0; rt < 2; ++rt) {
            int arow = wv * 32 + rt * 16 + c0l;
            ahi[rt] = *reinterpret_cast<const bf16x8*>(Ah + arow * LDSU + g * 8);
            alo[rt] = *reinterpret_cast<const bf16x8*>(Al + arow * LDSU + g * 8);
        }
#pragma unroll
        for (int ct = 0; ct < 8; ++ct) {
            int brow = ct * 16 + c0l;
            bf16x8 bhi = *reinterpret_cast<const bf16x8*>(Bh + brow * LDSU + g * 8);
            bf16x8 blo = *reinterpret_cast<const bf16x8*>(Bl + brow * LDSU + g * 8);
#pragma unroll
            for (int rt = 0; rt < 2; ++rt) {
                acc[rt][ct] = __builtin_amdgcn_mfma_f32_16x16x32_bf16(ahi[rt], bhi, acc[rt][ct], 0, 0, 0);
                acc[rt][ct] = __builtin_amdgcn_mfma_f32_16x16x32_bf16(ahi[rt], blo, acc[rt][ct], 0, 0, 0);
                acc[rt][ct] = __builtin_amdgcn_mfma_f32_16x16x32_bf16(alo[rt], bhi, acc[rt][ct], 0, 0, 0);
            }
        }
    }

    float ivb[8], ppc[8];
#pragma unroll
    for (int ct = 0; ct < 8; ++ct) {
        ivb[ct] = inv_s[cb + ct * 16 + c0l];
        ppc[ct] = pp[cb + ct * 16 + c0l];
    }
    float t3r[2][4][3];
#pragma unroll
    for (int rt = 0; rt < 2; ++rt)
#pragma unroll
        for (int v = 0; v < 4; ++v)
            t3r[rt][v][0] = t3r[rt][v][1] = t3r[rt][v][2] = INFINITY;
#pragma unroll
    for (int rt = 0; rt < 2; ++rt) {
        float iva[4], qqr[4];
#pragma unroll
        for (int v = 0; v < 4; ++v) {
            int row = rb + wv * 32 + rt * 16 + g * 4 + v;
            iva[v] = inv_q[row];
            qqr[v] = qq[row];
        }
#pragma unroll
        for (int ct = 0; ct < 8; ++ct) {
#pragma unroll
            for (int v = 0; v < 4; ++v) {
                float dot = acc[rt][ct][v] * iva[v] * ivb[ct];
                float d2 = qqr[v] + ppc[ct] - 2.0f * dot;
                float d = sqrtf(fmaxf(d2, 1e-12f));
                t3ins(t3r[rt][v], d);
            }
        }
    }
#pragma unroll
    for (int off = 1; off < 16; off <<= 1) {
#pragma unroll
        for (int rt = 0; rt < 2; ++rt)
#pragma unroll
            for (int v = 0; v < 4; ++v) {
                float o0 = __shfl_xor(t3r[rt][v][0], off, 64);
                float o1 = __shfl_xor(t3r[rt][v][1], off, 64);
                float o2 = __shfl_xor(t3r[rt][v][2], off, 64);
                t3ins(t3r[rt][v], o0);
                t3ins(t3r[rt][v], o1);
                t3ins(t3r[rt][v], o2);
            }
    }
    if (c0l == 0) {
#pragma unroll
        for (int rt = 0; rt < 2; ++rt)
#pragma unroll
            for (int v = 0; v < 4; ++v) {
                int row = rb + wv * 32 + rt * 16 + g * 4 + v;
                float* dst = top3part + ((size_t)cs * Q_ROWS + row) * 4;
                dst[0] = t3r[rt][v][0]; dst[1] = t3r[rt][v][1];
                dst[2] = t3r[rt][v][2]; dst[3] = 0.0f;
            }
    }
}

// ---------------------------------------------------------------------------
// Phase C: packed-word flag barrier (R18/R19) + NEW: each thread keeps its
// pre-scaled quarter-row (16 float4 = 64 VGPR) in REGISTERS for the whole
// kernel — per-candidate updates do 16 LDS reads + 64 FMA, zero global
// traffic inside the 20-iteration loop. rr[i] = v*si is bitwise the same
// (v.x*si) term the previous dot computed -> results unchanged.
__launch_bounds__(1024)
__global__ void iterate_select(const float* __restrict__ qf, const float* __restrict__ inv_q,
                               const float* __restrict__ qq, const float* __restrict__ top3part,
                               float* __restrict__ out, float* __restrict__ candU,
                               int* __restrict__ candI, unsigned long long* __restrict__ packed) {
    __shared__ float t3s[CR][3];
    __shared__ float qqs[CR], scs[CR];
    __shared__ int kn[CR];
    __shared__ __align__(16) float qfc[DIM];
    __shared__ float red[CT / 64];
    __shared__ float bmin_sh;
    __shared__ unsigned long long pk_sh[CB];
    __shared__ int lidx[16];
    __shared__ int lidx_loc[SLOTS];
    __shared__ int lcnt, ccnt;

    int tid = threadIdx.x;
    int bid = blockIdx.x;
    int rbase = bid * CR;
    int lane = tid & 63, wv = tid >> 6;
    int row = tid >> 2, sub = tid & 3;   // 4 threads per row

    // resident pre-scaled quarter-row (loaded once; bitwise = (v*si) terms)
    float4 rr[16];
    {
        float si = inv_q[rbase + row];
        const float4* rp = reinterpret_cast<const float4*>(qf + (size_t)(rbase + row) * DIM);
#pragma unroll
        for (int i = 0; i < 16; ++i) {
            float4 v = rp[sub + 4 * i];
            rr[i] = make_float4(v.x * si, v.y * si, v.z * si, v.w * si);
        }
    }
    if (tid < CR) {
        int r = rbase + tid;
        float b3[3] = {INFINITY, INFINITY, INFINITY};
        for (int csq = 0; csq < COLSPLIT; ++csq) {
            const float* p = top3part + ((size_t)csq * Q_ROWS + r) * 4;
            t3ins(b3, p[0]); t3ins(b3, p[1]); t3ins(b3, p[2]);
        }
        t3s[tid][0] = b3[0]; t3s[tid][1] = b3[1]; t3s[tid][2] = b3[2];
        qqs[tid] = qq[r];
        kn[tid] = 0;
    }
    __syncthreads();

    for (int t = 0; t <= N_SEL; ++t) {
        if (t > 0) {
            if (tid == 0) lcnt = 0;
            __syncthreads();
            if (wv == 0) {
                unsigned long long pv = (lane < CB) ? pk_sh[lane] : ~0ull;
                unsigned bb = (lane < CB) ? (unsigned)(pv >> 32) : 0xFFFFFFFFu;
                unsigned mb = bb;
#pragma unroll
                for (int o = 1; o < 64; o <<= 1) mb = min(mb, (unsigned)__shfl_xor((int)mb, o, 64));
                if (lane < CB && bb == mb) {
                    if (!(pv & 1ull)) {
                        int p = atomicAdd(&lcnt, 1);
                        if (p < 16) lidx[p] = (int)((pv >> 1) & 0x7FFFull);
                    } else {
                        for (int s2 = 0; s2 < SLOTS; ++s2) {
                            float u = candU[(t - 1) * CB * SLOTS + lane * SLOTS + s2];
                            if (__float_as_uint(u) == mb) {
                                int p = atomicAdd(&lcnt, 1);
                                if (p < 16) lidx[p] = candI[(t - 1) * CB * SLOTS + lane * SLOTS + s2];
                            }
                        }
                    }
                }
            }
            __syncthreads();
            int m = lcnt < 16 ? lcnt : 16;
            for (int j = 0; j < m; ++j) {
                int c = lidx[j];
                if (tid == 0 && c >= rbase && c < rbase + CR) kn[c - rbase] = 1;
                if (tid < 64) {
                    float4 v = reinterpret_cast<const float4*>(qf + (size_t)c * DIM)[tid];
                    float s = inv_q[c];
                    reinterpret_cast<float4*>(qfc)[tid] = make_float4(v.x * s, v.y * s, v.z * s, v.w * s);
                }
                __syncthreads();
                float qqc = qq[c];
                const float4* cp = reinterpret_cast<const float4*>(qfc);
                float d = 0.0f;
#pragma unroll
                for (int i2 = 0; i2 < 16; ++i2) {
                    float4 w = cp[sub + 4 * i2];
                    d += rr[i2].x * w.x;
                    d += rr[i2].y * w.y;
                    d += rr[i2].z * w.z;
                    d += rr[i2].w * w.w;
                }
                d += __shfl_xor(d, 1, 64);
                d += __shfl_xor(d, 2, 64);
                if (sub == 0) {
                    float d2 = qqs[row] + qqc - 2.0f * d;
                    float dist = sqrtf(fmaxf(d2, 1e-12f));
                    float b3[3] = {t3s[row][0], t3s[row][1], t3s[row][2]};
                    t3ins(b3, dist);
                    t3s[row][0] = b3[0]; t3s[row][1] = b3[1]; t3s[row][2] = b3[2];
                }
                __syncthreads();
            }
            __syncthreads();
        }

        if (t == N_SEL) {
            if (tid < CR)
                out[rbase + tid] = 1.0f - smean3(t3s[tid][0], t3s[tid][1], t3s[tid][2]);
            return;
        }

        // scores (inf = known)
        if (tid == 0) ccnt = 0;
        if (tid < CR)
            scs[tid] = kn[tid] ? INFINITY : smean3(t3s[tid][0], t3s[tid][1], t3s[tid][2]);
        __syncthreads();

        // block min
        float mn = (tid < CR) ? scs[tid] : INFINITY;
#pragma unroll
        for (int o = 1; o < 64; o <<= 1) mn = fminf(mn, __shfl_xor(mn, o, 64));
        if (lane == 0) red[wv] = mn;
        __syncthreads();
        if (tid == 0) {
            float v = red[0];
#pragma unroll
            for (int i = 1; i < CT / 64; ++i) v = fminf(v, red[i]);
            bmin_sh = v;
        }
        __syncthreads();
        float bmin = bmin_sh;
        if (tid < CR && scs[tid] == bmin) {
            int p = atomicAdd(&ccnt, 1);
            if (p < SLOTS) {
                candU[t * CB * SLOTS + bid * SLOTS + p] = scs[tid];
                candI[t * CB * SLOTS + bid * SLOTS + p] = rbase + tid;
                lidx_loc[p] = rbase + tid;
            }
        }
        __syncthreads();
        if (tid == 0) {
            for (int p = ccnt; p < SLOTS; ++p) {
                candU[t * CB * SLOTS + bid * SLOTS + p] = INFINITY;
                candI[t * CB * SLOTS + bid * SLOTS + p] = 0;
            }
            unsigned long long pk = ((unsigned long long)__float_as_uint(bmin) << 32)
                                  | ((unsigned long long)(unsigned)lidx_loc[0] << 1)
                                  | (ccnt > 1 ? 1ull : 0ull);
            __hip_atomic_store(&packed[(t * CB + bid) * PKS], pk,
                               __ATOMIC_RELEASE, __HIP_MEMORY_SCOPE_AGENT);
        }
        // barrier == poll packed[t] into LDS; acquire-only agent fence after
        if (wv == 0) {
            for (;;) {
                unsigned long long pv = (lane < CB)
                    ? __hip_atomic_load(&packed[(t * CB + lane) * PKS], __ATOMIC_RELAXED, __HIP_MEMORY_SCOPE_AGENT)
                    : 0ull;
                bool ok = (lane >= CB) || (pv != ~0ull);
                if (__all(ok)) { if (lane < CB) pk_sh[lane] = pv; break; }
                __builtin_amdgcn_s_sleep(1);
            }
            __builtin_amdgcn_fence(__ATOMIC_ACQUIRE, "agent");
        }
        __syncthreads();
    }
}

// ---------------------------------------------------------------------------
extern "C" void kernel_launch(void* const* d_in, const int* in_sizes, int n_in,
                              void* d_out, int out_size, void* d_ws, size_t ws_size,
                              hipStream_t stream) {
    const float* sfeat = (const float*)d_in[0];
    const float* qfeat = (const float*)d_in[2];
    float* out = (float*)d_out;

    float* ws = (float*)d_ws;
    float* inv_q = ws + WS_INV_Q;
    float* qq    = ws + WS_QQ;
    float* inv_s = ws + WS_INV_S;
    float* pp    = ws + WS_PP;
    float* top3p = ws + WS_TOP3P;
    float* candU = ws + WS_CANDU;
    int* candI   = (int*)(ws + WS_CANDI);
    unsigned long long* packed = (unsigned long long*)(ws + WS_PACKED);

    int n_extra = out_size - Q_ROWS;
    if (n_extra < 0) n_extra = 0;

    norm_rows_all<<<(Q_ROWS + S_ROWS) * 64 / 256, 256, 0, stream>>>(qfeat, sfeat, inv_q, qq, inv_s, pp);
    init_ws<<<32, 256, 0, stream>>>(packed, out, n_extra);  // 8192 threads >= max(32*CB, n_extra)
    knn_support_kernel<<<64 * COLSPLIT, 256, 0, stream>>>(qfeat, sfeat, inv_q, inv_s, qq, pp, top3p);

    const float* a0 = qfeat; const float* a1 = inv_q; const float* a2 = qq;
    const float* a3 = top3p; float* a4 = out;
    float* a5 = candU; int* a6 = candI; unsigned long long* a7 = packed;
    void* cargs[] = {&a0, &a1, &a2, &a3, &a4, &a5, &a6, &a7};
    hipLaunchCooperativeKernel(iterate_select, dim3(CB), dim3(CT), cargs, 0, stream);
}